// Round 6
// baseline (314.579 us; speedup 1.0000x reference)
//
#include <hip/hip_runtime.h>

// GCN 2-layer + mean-pool + readout.
// Algebra: aggregation is linear, so transform FIRST:
//   Y      = (norm_out ⊙ X) @ W1            (dense register-tiled GEMM, fp32)
//   h1[n]  = relu( norm_in[n] * sum_{e:dst=n} Y[src_e] + b1 )
//   out    = ((1/N) * sum_u c[u]*h1[u]) @ W2 + b2  @ Wr^T + br
//   c[u]   = norm_out[u] * sum_{e:src=u} norm_in[dst_e]
//
// Round-5 insight: k_deg/k_scatter are bound by same-line serialization of
// device-scope atomics (avg degree 16 -> ~256 RMWs per 64B line). Fix:
// 8-way PRIVATIZED histograms (copy = blockIdx&7 = XCD id): deg_out8,
// deg_in8, c_raw8. k_norm folds copies and writes per-copy exclusive bases
// in place, so the counting sort stays exact:
//   pos = row_ptr[d] + base[copy][d] + rank_within_copy[e].
// Y stays fp32 in 8 column panels of 12 (2.4 MB, L2-resident per XCD).
//
// Pipeline: memset2 -> k_deg -> k_norm(fold+bases+partials) -> k_scanp ->
//           k_rowptr -> k_scatter -> k_cmerge -> k_xform -> k_agg -> k_final.

constexpr int NN = 50000;
constexpr int NE = 800000;

// ws layout in 4-byte units:
constexpr int OFF_SVEC     = 0;        // float[256]  (zeroed, memset1)
constexpr int OFF_PART     = 256;      // int[256]
constexpr int OFF_BOFF     = 512;      // int[256]
constexpr int OFF_NORM_OUT = 768;      // float[50000]
constexpr int OFF_NORM_IN  = 50768;    // float[50000]
constexpr int OFF_DIN_TOT  = 100768;   // int[50000]
constexpr int OFF_CW       = 150768;   // float[50000]
constexpr int OFF_ROW_PTR  = 200768;   // int[50001] -> pad to 250772
constexpr int OFF_EDGE_SRC = 250772;   // int[800000] -> 1050772
constexpr int OFF_RANK     = 1050772;  // int[800000] -> 1850772 (dead after k_scatter)
constexpr int OFF_YP       = 1050772;  // float[8][50000][12] aliases rank+privatized
                                       // (YP written in k_xform, after all die)
constexpr int OFF_DEG_OUT8 = 1850772;  // int[8][50000] (zeroed, memset2; dead after k_norm)
constexpr int OFF_DEG_IN8  = 2250772;  // int[8][50000] (zeroed; bases after k_norm)
constexpr int OFF_CRAW8    = 2650772;  // float[8][50000] (zeroed; dead after k_cmerge)
// privatized region end: 3050772; YP end: 5850772 (23.4 MB peak)

__global__ void k_deg(const int* __restrict__ src, const int* __restrict__ dst,
                      int* __restrict__ deg_out8, int* __restrict__ deg_in8,
                      int* __restrict__ rank) {
  int e = blockIdx.x * blockDim.x + threadIdx.x;
  int k = blockIdx.x & 7;                       // privatized copy = XCD id
  if (e < NE) {
    atomicAdd(&deg_out8[k * NN + src[e]], 1);
    rank[e] = atomicAdd(&deg_in8[k * NN + dst[e]], 1);  // within-copy rank
  }
}

// Fold privatized histograms: norms, deg_in totals, per-copy exclusive bases
// (written back into deg_in8), block partial sums for the scan.
__global__ void k_norm(const int* __restrict__ deg_out8, int* __restrict__ deg_in8,
                       float* __restrict__ norm_out, float* __restrict__ norm_in,
                       int* __restrict__ din_tot, int* __restrict__ partials) {
  __shared__ int sred[256];
  int t = threadIdx.x;
  int n = blockIdx.x * 256 + t;
  int di = 0;
  if (n < NN) {
    int so = 0;
#pragma unroll
    for (int k = 0; k < 8; ++k) so += deg_out8[k * NN + n];
    int run = 0;
#pragma unroll
    for (int k = 0; k < 8; ++k) {
      int c = deg_in8[k * NN + n];
      deg_in8[k * NN + n] = run;               // exclusive base of copy k
      run += c;
    }
    di = run;
    norm_out[n] = 1.0f / sqrtf((float)max(so, 1));
    norm_in[n]  = 1.0f / sqrtf((float)max(di, 1));
    din_tot[n]  = di;
  }
  sred[t] = di;
  __syncthreads();
  for (int s = 128; s > 0; s >>= 1) {
    if (t < s) sred[t] += sred[t + s];
    __syncthreads();
  }
  if (t == 0) partials[blockIdx.x] = sred[0];
}

// exclusive scan of the 196 block partials (1 block)
__global__ void k_scanp(const int* __restrict__ partials, int* __restrict__ block_off,
                        int* __restrict__ row_ptr) {
  __shared__ int sc[256];
  int t = threadIdx.x;
  int v = (t < 196) ? partials[t] : 0;
  sc[t] = v;
  __syncthreads();
  for (int off = 1; off < 256; off <<= 1) {
    int u = (t >= off) ? sc[t - off] : 0;
    __syncthreads();
    sc[t] += u;
    __syncthreads();
  }
  block_off[t] = sc[t] - v;          // exclusive prefix
  if (t == 255) row_ptr[NN] = sc[255];
}

// row_ptr via per-block scan of deg_in totals.
__global__ void k_rowptr(const int* __restrict__ din_tot, const int* __restrict__ block_off,
                         int* __restrict__ row_ptr) {
  __shared__ int sc[256];
  int t = threadIdx.x;
  int idx = blockIdx.x * 256 + t;
  int d = (idx < NN) ? din_tot[idx] : 0;
  sc[t] = d;
  __syncthreads();
  for (int off = 1; off < 256; off <<= 1) {
    int u = (t >= off) ? sc[t - off] : 0;
    __syncthreads();
    sc[t] += u;
    __syncthreads();
  }
  int base = block_off[blockIdx.x] + (sc[t] - d);
  if (idx < NN) row_ptr[idx] = base;
}

// Place edges: pos = row_ptr[d] + base[copy][d] + rank[e]; privatized c_raw.
// Copy index matches k_deg (same grid -> same blockIdx for a given e).
__global__ void k_scatter(const int* __restrict__ src, const int* __restrict__ dst,
                          const int* __restrict__ rank, const int* __restrict__ row_ptr,
                          const int* __restrict__ deg_in8,       // per-copy bases
                          const float* __restrict__ norm_in,
                          int* __restrict__ edge_src, float* __restrict__ c_raw8) {
  int e = blockIdx.x * blockDim.x + threadIdx.x;
  int k = blockIdx.x & 7;
  if (e < NE) {
    int d = dst[e], s = src[e];
    edge_src[row_ptr[d] + deg_in8[k * NN + d] + rank[e]] = s;
    atomicAdd(&c_raw8[k * NN + s], norm_in[d]);
  }
}

// cw[n] = norm_out[n] * sum_k c_raw8[k][n]
__global__ void k_cmerge(const float* __restrict__ c_raw8,
                         const float* __restrict__ norm_out, float* __restrict__ cw) {
  int n = blockIdx.x * 256 + threadIdx.x;
  if (n < NN) {
    float s = 0.f;
#pragma unroll
    for (int k = 0; k < 8; ++k) s += c_raw8[k * NN + n];
    cw[n] = norm_out[n] * s;
  }
}

// Y = (norm_out ⊙ X) @ W1 — register-tiled GEMM, panel-layout fp32 output.
// One 64-node tile per block. X-tile staged TRANSPOSED in LDS (26 KB).
// Thread (tn=t&7, tm=t>>3) computes 2 nodes x 12 cols; tn IS the panel.
__global__ __launch_bounds__(256, 6)
void k_xform(const float* __restrict__ feats, const float* __restrict__ norm_out,
             const float* __restrict__ W1, float* __restrict__ YP) {
  __shared__ float XT[96][68];            // [k][node], pad 64->68
  const int t = threadIdx.x;
  const int nb = blockIdx.x * 64;         // tile base node

  // ---- stage: coalesced float4 global reads -> transposed LDS writes ----
  const float4* f4 = (const float4*)feats;
#pragma unroll
  for (int i = 0; i < 6; ++i) {           // 6*256 = 1536 float4 = 64x96 floats
    int idx4 = i * 256 + t;
    int n = idx4 / 24;                    // node within tile (24 float4 per row)
    int kq = idx4 % 24;
    int ng = nb + n;
    float4 v = make_float4(0.f, 0.f, 0.f, 0.f);
    float no = 0.f;
    if (ng < NN) { v = f4[(size_t)ng * 24 + kq]; no = norm_out[ng]; }
    XT[kq * 4 + 0][n] = v.x * no;
    XT[kq * 4 + 1][n] = v.y * no;
    XT[kq * 4 + 2][n] = v.z * no;
    XT[kq * 4 + 3][n] = v.w * no;
  }
  __syncthreads();

  // ---- compute: 2 nodes x 12 cols per thread ----
  const int tn = t & 7;                   // panel / column chunk: cols 12*tn..
  const int tm = t >> 3;                  // node pair: nodes 2*tm, 2*tm+1
  float acc0[12], acc1[12];
#pragma unroll
  for (int c = 0; c < 12; ++c) { acc0[c] = 0.f; acc1[c] = 0.f; }

  const float4* W4 = (const float4*)(W1 + 12 * tn);   // row stride 24 float4
#pragma unroll 4
  for (int k = 0; k < 96; ++k) {
    float2 x = *(const float2*)&XT[k][2 * tm];
    float4 w0 = W4[k * 24 + 0];
    float4 w1 = W4[k * 24 + 1];
    float4 w2 = W4[k * 24 + 2];
    const float w[12] = {w0.x, w0.y, w0.z, w0.w, w1.x, w1.y, w1.z, w1.w,
                         w2.x, w2.y, w2.z, w2.w};
#pragma unroll
    for (int c = 0; c < 12; ++c) {
      acc0[c] = fmaf(x.x, w[c], acc0[c]);
      acc1[c] = fmaf(x.y, w[c], acc1[c]);
    }
  }

  // ---- store into panel tn: 12 contiguous floats per node ----
  int n0 = nb + 2 * tm;
  if (n0 < NN) {
    float4* yp = (float4*)(YP + ((size_t)tn * NN + n0) * 12);
    yp[0] = make_float4(acc0[0], acc0[1], acc0[2], acc0[3]);
    yp[1] = make_float4(acc0[4], acc0[5], acc0[6], acc0[7]);
    yp[2] = make_float4(acc0[8], acc0[9], acc0[10], acc0[11]);
  }
  if (n0 + 1 < NN) {
    float4* yp = (float4*)(YP + ((size_t)tn * NN + n0 + 1) * 12);
    yp[0] = make_float4(acc1[0], acc1[1], acc1[2], acc1[3]);
    yp[1] = make_float4(acc1[4], acc1[5], acc1[6], acc1[7]);
    yp[2] = make_float4(acc1[8], acc1[9], acc1[10], acc1[11]);
  }
}

// Panel-per-XCD CSR gather. Block b works on panel p = b%8 (lands on XCD p by
// round-robin dispatch), sweeping ALL nodes but only cols [12p,12p+12).
// Panel = 2.4 MB -> L2-resident in its XCD; gathers become L2 hits.
// Lane layout: l<24 active, edge-slot ei=l/3 (8 edges/step), quad q=l%3
// (cols 4q..4q+3 via one float4). Cross-slot reduce: shfl +12,+6,+3.
__global__ __launch_bounds__(256, 8)
void k_agg(const float* __restrict__ YP,
           const float* __restrict__ norm_in, const float* __restrict__ cw,
           const int* __restrict__ row_ptr, const int* __restrict__ edge_src,
           const float* __restrict__ b1, float* __restrict__ svec) {
  __shared__ float red[12];
  const int tid = threadIdx.x;
  if (tid < 12) red[tid] = 0.f;
  __syncthreads();

  const int panel = blockIdx.x & 7;
  const int bp    = blockIdx.x >> 3;        // block index within panel (0..255)
  const int g = tid >> 5, l = tid & 31;
  const int ei = l / 3;                     // edge slot 0..7 (l<24)
  const int q  = l - 3 * ei;                // float4 index within 12-col row
  const bool act = (l < 24);

  const float* Yp = YP + (size_t)panel * NN * 12;
  float4 b4 = make_float4(0.f, 0.f, 0.f, 0.f);
  if (l < 3) b4 = ((const float4*)b1)[3 * panel + l];  // cols 12p+4l..+3

  float a0 = 0.f, a1 = 0.f, a2 = 0.f, a3 = 0.f;        // svec partials (l<3)

  const int gid = bp * 8 + g;               // 0..2047
  for (int n = gid; n < NN; n += 2048) {
    int e0 = row_ptr[n], e1 = row_ptr[n + 1];
    float v0 = 0.f, v1 = 0.f, v2 = 0.f, v3 = 0.f;
    for (int base = e0; base < e1; base += 32) {
      int idx = base + l;
      int es = (idx < e1) ? edge_src[idx] : 0;
      int cnt = min(32, e1 - base);
      // 4 sub-steps of 8 edges; all loads independent (ILP)
      int s0 = __shfl(es, ei, 32);
      int s1 = __shfl(es, 8 + ei, 32);
      int s2 = __shfl(es, 16 + ei, 32);
      int s3 = __shfl(es, 24 + ei, 32);
      float4 f0 = make_float4(0.f, 0.f, 0.f, 0.f), f1 = f0, f2 = f0, f3 = f0;
      if (act && ei < cnt)      f0 = *(const float4*)(Yp + (size_t)s0 * 12 + 4 * q);
      if (act && 8 + ei < cnt)  f1 = *(const float4*)(Yp + (size_t)s1 * 12 + 4 * q);
      if (act && 16 + ei < cnt) f2 = *(const float4*)(Yp + (size_t)s2 * 12 + 4 * q);
      if (act && 24 + ei < cnt) f3 = *(const float4*)(Yp + (size_t)s3 * 12 + 4 * q);
      v0 += (f0.x + f1.x) + (f2.x + f3.x);
      v1 += (f0.y + f1.y) + (f2.y + f3.y);
      v2 += (f0.z + f1.z) + (f2.z + f3.z);
      v3 += (f0.w + f1.w) + (f2.w + f3.w);
    }
    // reduce across the 8 edge slots: lanes 3k+q sum into k=0 (lanes 0..2).
    v0 += __shfl(v0, l + 12, 32); v1 += __shfl(v1, l + 12, 32);
    v2 += __shfl(v2, l + 12, 32); v3 += __shfl(v3, l + 12, 32);
    v0 += __shfl(v0, l + 6, 32);  v1 += __shfl(v1, l + 6, 32);
    v2 += __shfl(v2, l + 6, 32);  v3 += __shfl(v3, l + 6, 32);
    v0 += __shfl(v0, l + 3, 32);  v1 += __shfl(v1, l + 3, 32);
    v2 += __shfl(v2, l + 3, 32);  v3 += __shfl(v3, l + 3, 32);

    if (l < 3) {
      float ni = norm_in[n];
      float c  = cw[n];
      a0 += c * fmaxf(fmaf(ni, v0, b4.x), 0.f);
      a1 += c * fmaxf(fmaf(ni, v1, b4.y), 0.f);
      a2 += c * fmaxf(fmaf(ni, v2, b4.z), 0.f);
      a3 += c * fmaxf(fmaf(ni, v3, b4.w), 0.f);
    }
  }

  if (l < 3) {
    atomicAdd(&red[4 * l + 0], a0);
    atomicAdd(&red[4 * l + 1], a1);
    atomicAdd(&red[4 * l + 2], a2);
    atomicAdd(&red[4 * l + 3], a3);
  }
  __syncthreads();
  if (tid < 12) atomicAdd(&svec[12 * panel + tid], red[tid]);
}

// hg = (svec/N) @ W2 + b2 ; out = hg @ Wr^T + br
__global__ void k_final(const float* __restrict__ svec,
                        const float* __restrict__ W2, const float* __restrict__ b2,
                        const float* __restrict__ Wr, const float* __restrict__ br,
                        float* __restrict__ out) {
  __shared__ float hg[96];
  int j = threadIdx.x;
  if (j < 96) {
    float acc = b2[j];
    const float invN = 1.0f / (float)NN;
    for (int k = 0; k < 96; ++k)
      acc = fmaf(svec[k] * invN, W2[k * 96 + j], acc);
    hg[j] = acc;
  }
  __syncthreads();
  if (j < 8) {
    float acc = br[j];
    for (int k = 0; k < 96; ++k)
      acc = fmaf(hg[k], Wr[j * 96 + k], acc);
    out[j] = acc;
  }
}

extern "C" void kernel_launch(void* const* d_in, const int* in_sizes, int n_in,
                              void* d_out, int out_size, void* d_ws, size_t ws_size,
                              hipStream_t stream) {
  const float* feats = (const float*)d_in[0];
  const int*   src   = (const int*)d_in[1];
  const int*   dst   = (const int*)d_in[2];
  const float* W1    = (const float*)d_in[3];
  const float* b1    = (const float*)d_in[4];
  const float* W2    = (const float*)d_in[5];
  const float* b2    = (const float*)d_in[6];
  const float* Wr    = (const float*)d_in[7];
  const float* br    = (const float*)d_in[8];
  float* out = (float*)d_out;

  int*   wsi      = (int*)d_ws;
  float* wsf      = (float*)d_ws;
  float* svec     = wsf + OFF_SVEC;
  int*   partials = wsi + OFF_PART;
  int*   block_off= wsi + OFF_BOFF;
  float* norm_out = wsf + OFF_NORM_OUT;
  float* norm_in  = wsf + OFF_NORM_IN;
  int*   din_tot  = wsi + OFF_DIN_TOT;
  float* cw       = wsf + OFF_CW;
  int*   row_ptr  = wsi + OFF_ROW_PTR;
  int*   edge_src = wsi + OFF_EDGE_SRC;
  int*   rank     = wsi + OFF_RANK;
  float* YP       = wsf + OFF_YP;        // aliases rank + privatized arrays
  int*   deg_out8 = wsi + OFF_DEG_OUT8;
  int*   deg_in8  = wsi + OFF_DEG_IN8;
  float* c_raw8   = wsf + OFF_CRAW8;

  hipMemsetAsync(svec, 0, 256 * 4, stream);
  hipMemsetAsync(deg_out8, 0, (size_t)(3050772 - 1850772) * 4, stream);  // 3 privatized arrays

  k_deg<<<(NE + 255) / 256, 256, 0, stream>>>(src, dst, deg_out8, deg_in8, rank);
  k_norm<<<(NN + 255) / 256, 256, 0, stream>>>(deg_out8, deg_in8, norm_out, norm_in,
                                               din_tot, partials);
  k_scanp<<<1, 256, 0, stream>>>(partials, block_off, row_ptr);
  k_rowptr<<<(NN + 255) / 256, 256, 0, stream>>>(din_tot, block_off, row_ptr);
  k_scatter<<<(NE + 255) / 256, 256, 0, stream>>>(src, dst, rank, row_ptr, deg_in8,
                                                  norm_in, edge_src, c_raw8);
  k_cmerge<<<(NN + 255) / 256, 256, 0, stream>>>(c_raw8, norm_out, cw);
  k_xform<<<(NN + 63) / 64, 256, 0, stream>>>(feats, norm_out, W1, YP);
  k_agg<<<2048, 256, 0, stream>>>(YP, norm_in, cw, row_ptr, edge_src, b1, svec);
  k_final<<<1, 128, 0, stream>>>(svec, W2, b2, Wr, br, out);
}

// Round 7
// 282.201 us; speedup vs baseline: 1.1147x; 1.1147x over previous
//
#include <hip/hip_runtime.h>

// GCN 2-layer + mean-pool + readout.
// Algebra: aggregation is linear, so transform FIRST:
//   Y      = (norm_out ⊙ X) @ W1            (dense register-tiled GEMM, fp32)
//   h1[n]  = relu( norm_in[n] * sum_{e:dst=n} Y[src_e] + b1 )
//   out    = ((1/N) * sum_u c[u]*h1[u]) @ W2 + b2  @ Wr^T + br
//   c[u]   = norm_out[u] * sum_{e:src=u} norm_in[dst_e]
//
// Round-6 insight: device-scope atomics cost one 64B line move at the
// coherence point PER ATOMIC (WRITE_SIZE == NE*64B; privatization didn't
// help). So: NO per-edge global atomics. Two-level binning instead:
//   k_part   : one pass, partition edges into 49 buckets of 1024 nodes by
//              dst AND by src (packed 26-bit entries). Per-block LDS hist +
//              49 cursor reservations -> 77K global atomics total (30x cut).
//   k_bin_dst: per bucket, LDS histogram -> deg_in + scan partials.
//   k_place  : per bucket, LDS cursors (init row_ptr) -> CSR edge_src.
//   k_bin_src: per bucket, LDS deg_out + c_raw(+norm_in gather) -> norm_out, cw.
// All per-edge atomic work is LDS-local. Y stays fp32 in 8 column panels
// (2.4 MB each, L2-resident per XCD; k_agg panel-per-XCD as round 5).
//
// Pipeline: memset(1.5KB) -> k_part -> k_bin_dst -> k_scanp -> k_rowptr(+norm_in)
//           -> k_place -> k_bin_src -> k_xform -> k_agg -> k_final.

constexpr int NN = 50000;
constexpr int NE = 800000;
constexpr int NB = 49;          // buckets of 1024 nodes (dst>>10 / src>>10)
constexpr int CAP = 24576;      // bucket capacity (mean 16384, +64 sigma)

// ws layout in 4-byte units:
constexpr int OFF_SVEC     = 0;        // float[256]  (zeroed)
constexpr int OFF_BCURD    = 256;      // int[64]     (zeroed)
constexpr int OFF_BCURS    = 320;      // int[64]     (zeroed)
constexpr int OFF_PART     = 384;      // int[256]
constexpr int OFF_BOFF     = 640;      // int[256]
constexpr int OFF_NORM_OUT = 896;      // float[50000]
constexpr int OFF_NORM_IN  = 50896;    // float[50000]
constexpr int OFF_CW       = 100896;   // float[50000]
constexpr int OFF_DEG_IN   = 150896;   // int[50000]
constexpr int OFF_ROW_PTR  = 200896;   // int[50001] -> pad 250900
constexpr int OFF_EDGE_SRC = 250900;   // int[800000] -> 1050900
constexpr int OFF_PD       = 1050900;  // int[49*24576] (dead after k_place)
constexpr int OFF_PS       = 2255124;  // int[49*24576] (dead after k_bin_src)
constexpr int OFF_YP       = 1050900;  // float[8][50000][12] aliases PD+PS
                                       // (k_xform runs after both are dead)
constexpr size_t ZERO_BYTES = (size_t)(OFF_PART) * 4;   // svec + cursors

// One-pass dual partition (by dst bucket and by src bucket).
__global__ __launch_bounds__(256)
void k_part(const int* __restrict__ src, const int* __restrict__ dst,
            int* __restrict__ bcur_d, int* __restrict__ bcur_s,
            int* __restrict__ pd, int* __restrict__ ps) {
  __shared__ int hd[64], hs[64], cd[64], cs[64];
  const int t = threadIdx.x;
  if (t < 64) { hd[t] = 0; hs[t] = 0; }
  __syncthreads();
  const int e0 = blockIdx.x * 1024;
  int s_[4], d_[4];
#pragma unroll
  for (int i = 0; i < 4; ++i) {
    int e = e0 + i * 256 + t;
    bool v = e < NE;
    s_[i] = v ? src[e] : -1;
    d_[i] = v ? dst[e] : -1;
    if (v) { atomicAdd(&hd[d_[i] >> 10], 1); atomicAdd(&hs[s_[i] >> 10], 1); }
  }
  __syncthreads();
  if (t < 64) {
    int c = hd[t];
    cd[t] = c ? (t * CAP + atomicAdd(&bcur_d[t], c)) : 0;
    c = hs[t];
    cs[t] = c ? (t * CAP + atomicAdd(&bcur_s[t], c)) : 0;
  }
  __syncthreads();
#pragma unroll
  for (int i = 0; i < 4; ++i) {
    if (s_[i] >= 0) {
      int pos = atomicAdd(&cd[d_[i] >> 10], 1);     // LDS
      pd[pos] = (s_[i] << 10) | (d_[i] & 1023);
      int pos2 = atomicAdd(&cs[s_[i] >> 10], 1);    // LDS
      ps[pos2] = (d_[i] << 10) | (s_[i] & 1023);
    }
  }
}

// Per-bucket in-degree histogram (LDS atomics) + per-256-node scan partials.
__global__ __launch_bounds__(256)
void k_bin_dst(const int* __restrict__ pd, const int* __restrict__ bcur_d,
               int* __restrict__ deg_in, int* __restrict__ partials) {
  __shared__ int hist[1024];
  __shared__ int sred[256];
  const int t = threadIdx.x, b = blockIdx.x;
  for (int i = t; i < 1024; i += 256) hist[i] = 0;
  __syncthreads();
  const int cnt = bcur_d[b];
  const int* pe = pd + b * CAP;
  for (int i = t; i < cnt; i += 256) atomicAdd(&hist[pe[i] & 1023], 1);
  __syncthreads();
  const int nb = b * 1024;
#pragma unroll
  for (int j = 0; j < 4; ++j) {
    int idx = j * 256 + t, n = nb + idx;
    int v = hist[idx];
    if (n < NN) deg_in[n] = v;
    sred[t] = v;
    __syncthreads();
    for (int s = 128; s > 0; s >>= 1) {
      if (t < s) sred[t] += sred[t + s];
      __syncthreads();
    }
    if (t == 0) partials[b * 4 + j] = sred[0];
    __syncthreads();
  }
}

// exclusive scan of the 196 block partials (1 block)
__global__ void k_scanp(const int* __restrict__ partials, int* __restrict__ block_off,
                        int* __restrict__ row_ptr) {
  __shared__ int sc[256];
  int t = threadIdx.x;
  int v = (t < 196) ? partials[t] : 0;
  sc[t] = v;
  __syncthreads();
  for (int off = 1; off < 256; off <<= 1) {
    int u = (t >= off) ? sc[t - off] : 0;
    __syncthreads();
    sc[t] += u;
    __syncthreads();
  }
  block_off[t] = sc[t] - v;          // exclusive prefix
  if (t == 255) row_ptr[NN] = sc[255];
}

// row_ptr via per-block scan of deg_in; also emits norm_in.
__global__ void k_rowptr(const int* __restrict__ deg_in, const int* __restrict__ block_off,
                         int* __restrict__ row_ptr, float* __restrict__ norm_in) {
  __shared__ int sc[256];
  int t = threadIdx.x;
  int idx = blockIdx.x * 256 + t;
  int d = (idx < NN) ? deg_in[idx] : 0;
  sc[t] = d;
  __syncthreads();
  for (int off = 1; off < 256; off <<= 1) {
    int u = (t >= off) ? sc[t - off] : 0;
    __syncthreads();
    sc[t] += u;
    __syncthreads();
  }
  int base = block_off[blockIdx.x] + (sc[t] - d);
  if (idx < NN) {
    row_ptr[idx] = base;
    norm_in[idx] = 1.0f / sqrtf((float)max(d, 1));
  }
}

// Per-bucket CSR placement via LDS cursors (bucket rows are contiguous in
// edge_src, so the random writes stay within a ~64KB L2-local window).
__global__ __launch_bounds__(256)
void k_place(const int* __restrict__ pd, const int* __restrict__ bcur_d,
             const int* __restrict__ row_ptr, int* __restrict__ edge_src) {
  __shared__ int cur[1024];
  const int t = threadIdx.x, b = blockIdx.x, nb = b * 1024;
  for (int i = t; i < 1024; i += 256) {
    int n = nb + i;
    cur[i] = (n < NN) ? row_ptr[n] : 0;
  }
  __syncthreads();
  const int cnt = bcur_d[b];
  const int* pe = pd + b * CAP;
  for (int i = t; i < cnt; i += 256) {
    int p = pe[i];
    int pos = atomicAdd(&cur[p & 1023], 1);   // LDS
    edge_src[pos] = p >> 10;
  }
}

// Per-bucket out-degree + c_raw (LDS atomics; norm_in gathers are L2-hot),
// emits norm_out and cw = norm_out * c_raw.
__global__ __launch_bounds__(256)
void k_bin_src(const int* __restrict__ ps, const int* __restrict__ bcur_s,
               const float* __restrict__ norm_in,
               float* __restrict__ norm_out, float* __restrict__ cw) {
  __shared__ int dout[1024];
  __shared__ float craw[1024];
  const int t = threadIdx.x, b = blockIdx.x, nb = b * 1024;
  for (int i = t; i < 1024; i += 256) { dout[i] = 0; craw[i] = 0.f; }
  __syncthreads();
  const int cnt = bcur_s[b];
  const int* pe = ps + b * CAP;
  for (int i = t; i < cnt; i += 256) {
    int p = pe[i];
    int sl = p & 1023, dg = p >> 10;
    atomicAdd(&dout[sl], 1);                  // LDS
    atomicAdd(&craw[sl], norm_in[dg]);        // LDS float add
  }
  __syncthreads();
  for (int i = t; i < 1024; i += 256) {
    int n = nb + i;
    if (n < NN) {
      float no = 1.0f / sqrtf((float)max(dout[i], 1));
      norm_out[n] = no;
      cw[n] = no * craw[i];
    }
  }
}

// Y = (norm_out ⊙ X) @ W1 — register-tiled GEMM, panel-layout fp32 output.
// One 64-node tile per block. X-tile staged TRANSPOSED in LDS (26 KB).
// Thread (tn=t&7, tm=t>>3) computes 2 nodes x 12 cols; tn IS the panel.
__global__ __launch_bounds__(256, 6)
void k_xform(const float* __restrict__ feats, const float* __restrict__ norm_out,
             const float* __restrict__ W1, float* __restrict__ YP) {
  __shared__ float XT[96][68];            // [k][node], pad 64->68
  const int t = threadIdx.x;
  const int nb = blockIdx.x * 64;         // tile base node

  const float4* f4 = (const float4*)feats;
#pragma unroll
  for (int i = 0; i < 6; ++i) {           // 6*256 = 1536 float4 = 64x96 floats
    int idx4 = i * 256 + t;
    int n = idx4 / 24;
    int kq = idx4 % 24;
    int ng = nb + n;
    float4 v = make_float4(0.f, 0.f, 0.f, 0.f);
    float no = 0.f;
    if (ng < NN) { v = f4[(size_t)ng * 24 + kq]; no = norm_out[ng]; }
    XT[kq * 4 + 0][n] = v.x * no;
    XT[kq * 4 + 1][n] = v.y * no;
    XT[kq * 4 + 2][n] = v.z * no;
    XT[kq * 4 + 3][n] = v.w * no;
  }
  __syncthreads();

  const int tn = t & 7;                   // panel / column chunk: cols 12*tn..
  const int tm = t >> 3;                  // node pair: nodes 2*tm, 2*tm+1
  float acc0[12], acc1[12];
#pragma unroll
  for (int c = 0; c < 12; ++c) { acc0[c] = 0.f; acc1[c] = 0.f; }

  const float4* W4 = (const float4*)(W1 + 12 * tn);   // row stride 24 float4
#pragma unroll 4
  for (int k = 0; k < 96; ++k) {
    float2 x = *(const float2*)&XT[k][2 * tm];
    float4 w0 = W4[k * 24 + 0];
    float4 w1 = W4[k * 24 + 1];
    float4 w2 = W4[k * 24 + 2];
    const float w[12] = {w0.x, w0.y, w0.z, w0.w, w1.x, w1.y, w1.z, w1.w,
                         w2.x, w2.y, w2.z, w2.w};
#pragma unroll
    for (int c = 0; c < 12; ++c) {
      acc0[c] = fmaf(x.x, w[c], acc0[c]);
      acc1[c] = fmaf(x.y, w[c], acc1[c]);
    }
  }

  int n0 = nb + 2 * tm;
  if (n0 < NN) {
    float4* yp = (float4*)(YP + ((size_t)tn * NN + n0) * 12);
    yp[0] = make_float4(acc0[0], acc0[1], acc0[2], acc0[3]);
    yp[1] = make_float4(acc0[4], acc0[5], acc0[6], acc0[7]);
    yp[2] = make_float4(acc0[8], acc0[9], acc0[10], acc0[11]);
  }
  if (n0 + 1 < NN) {
    float4* yp = (float4*)(YP + ((size_t)tn * NN + n0 + 1) * 12);
    yp[0] = make_float4(acc1[0], acc1[1], acc1[2], acc1[3]);
    yp[1] = make_float4(acc1[4], acc1[5], acc1[6], acc1[7]);
    yp[2] = make_float4(acc1[8], acc1[9], acc1[10], acc1[11]);
  }
}

// Panel-per-XCD CSR gather (round-5 design, unchanged).
__global__ __launch_bounds__(256, 8)
void k_agg(const float* __restrict__ YP,
           const float* __restrict__ norm_in, const float* __restrict__ cw,
           const int* __restrict__ row_ptr, const int* __restrict__ edge_src,
           const float* __restrict__ b1, float* __restrict__ svec) {
  __shared__ float red[12];
  const int tid = threadIdx.x;
  if (tid < 12) red[tid] = 0.f;
  __syncthreads();

  const int panel = blockIdx.x & 7;
  const int bp    = blockIdx.x >> 3;
  const int g = tid >> 5, l = tid & 31;
  const int ei = l / 3;
  const int q  = l - 3 * ei;
  const bool act = (l < 24);

  const float* Yp = YP + (size_t)panel * NN * 12;
  float4 b4 = make_float4(0.f, 0.f, 0.f, 0.f);
  if (l < 3) b4 = ((const float4*)b1)[3 * panel + l];

  float a0 = 0.f, a1 = 0.f, a2 = 0.f, a3 = 0.f;

  const int gid = bp * 8 + g;
  for (int n = gid; n < NN; n += 2048) {
    int e0 = row_ptr[n], e1 = row_ptr[n + 1];
    float v0 = 0.f, v1 = 0.f, v2 = 0.f, v3 = 0.f;
    for (int base = e0; base < e1; base += 32) {
      int idx = base + l;
      int es = (idx < e1) ? edge_src[idx] : 0;
      int cnt = min(32, e1 - base);
      int s0 = __shfl(es, ei, 32);
      int s1 = __shfl(es, 8 + ei, 32);
      int s2 = __shfl(es, 16 + ei, 32);
      int s3 = __shfl(es, 24 + ei, 32);
      float4 f0 = make_float4(0.f, 0.f, 0.f, 0.f), f1 = f0, f2 = f0, f3 = f0;
      if (act && ei < cnt)      f0 = *(const float4*)(Yp + (size_t)s0 * 12 + 4 * q);
      if (act && 8 + ei < cnt)  f1 = *(const float4*)(Yp + (size_t)s1 * 12 + 4 * q);
      if (act && 16 + ei < cnt) f2 = *(const float4*)(Yp + (size_t)s2 * 12 + 4 * q);
      if (act && 24 + ei < cnt) f3 = *(const float4*)(Yp + (size_t)s3 * 12 + 4 * q);
      v0 += (f0.x + f1.x) + (f2.x + f3.x);
      v1 += (f0.y + f1.y) + (f2.y + f3.y);
      v2 += (f0.z + f1.z) + (f2.z + f3.z);
      v3 += (f0.w + f1.w) + (f2.w + f3.w);
    }
    v0 += __shfl(v0, l + 12, 32); v1 += __shfl(v1, l + 12, 32);
    v2 += __shfl(v2, l + 12, 32); v3 += __shfl(v3, l + 12, 32);
    v0 += __shfl(v0, l + 6, 32);  v1 += __shfl(v1, l + 6, 32);
    v2 += __shfl(v2, l + 6, 32);  v3 += __shfl(v3, l + 6, 32);
    v0 += __shfl(v0, l + 3, 32);  v1 += __shfl(v1, l + 3, 32);
    v2 += __shfl(v2, l + 3, 32);  v3 += __shfl(v3, l + 3, 32);

    if (l < 3) {
      float ni = norm_in[n];
      float c  = cw[n];
      a0 += c * fmaxf(fmaf(ni, v0, b4.x), 0.f);
      a1 += c * fmaxf(fmaf(ni, v1, b4.y), 0.f);
      a2 += c * fmaxf(fmaf(ni, v2, b4.z), 0.f);
      a3 += c * fmaxf(fmaf(ni, v3, b4.w), 0.f);
    }
  }

  if (l < 3) {
    atomicAdd(&red[4 * l + 0], a0);
    atomicAdd(&red[4 * l + 1], a1);
    atomicAdd(&red[4 * l + 2], a2);
    atomicAdd(&red[4 * l + 3], a3);
  }
  __syncthreads();
  if (tid < 12) atomicAdd(&svec[12 * panel + tid], red[tid]);
}

// hg = (svec/N) @ W2 + b2 ; out = hg @ Wr^T + br
__global__ void k_final(const float* __restrict__ svec,
                        const float* __restrict__ W2, const float* __restrict__ b2,
                        const float* __restrict__ Wr, const float* __restrict__ br,
                        float* __restrict__ out) {
  __shared__ float hg[96];
  int j = threadIdx.x;
  if (j < 96) {
    float acc = b2[j];
    const float invN = 1.0f / (float)NN;
    for (int k = 0; k < 96; ++k)
      acc = fmaf(svec[k] * invN, W2[k * 96 + j], acc);
    hg[j] = acc;
  }
  __syncthreads();
  if (j < 8) {
    float acc = br[j];
    for (int k = 0; k < 96; ++k)
      acc = fmaf(hg[k], Wr[j * 96 + k], acc);
    out[j] = acc;
  }
}

extern "C" void kernel_launch(void* const* d_in, const int* in_sizes, int n_in,
                              void* d_out, int out_size, void* d_ws, size_t ws_size,
                              hipStream_t stream) {
  const float* feats = (const float*)d_in[0];
  const int*   src   = (const int*)d_in[1];
  const int*   dst   = (const int*)d_in[2];
  const float* W1    = (const float*)d_in[3];
  const float* b1    = (const float*)d_in[4];
  const float* W2    = (const float*)d_in[5];
  const float* b2    = (const float*)d_in[6];
  const float* Wr    = (const float*)d_in[7];
  const float* br    = (const float*)d_in[8];
  float* out = (float*)d_out;

  int*   wsi      = (int*)d_ws;
  float* wsf      = (float*)d_ws;
  float* svec     = wsf + OFF_SVEC;
  int*   bcur_d   = wsi + OFF_BCURD;
  int*   bcur_s   = wsi + OFF_BCURS;
  int*   partials = wsi + OFF_PART;
  int*   block_off= wsi + OFF_BOFF;
  float* norm_out = wsf + OFF_NORM_OUT;
  float* norm_in  = wsf + OFF_NORM_IN;
  float* cw       = wsf + OFF_CW;
  int*   deg_in   = wsi + OFF_DEG_IN;
  int*   row_ptr  = wsi + OFF_ROW_PTR;
  int*   edge_src = wsi + OFF_EDGE_SRC;
  int*   pd       = wsi + OFF_PD;
  int*   ps       = wsi + OFF_PS;
  float* YP       = wsf + OFF_YP;        // aliases pd+ps (both dead by k_xform)

  hipMemsetAsync(d_ws, 0, ZERO_BYTES, stream);   // svec + bucket cursors

  k_part<<<(NE + 1023) / 1024, 256, 0, stream>>>(src, dst, bcur_d, bcur_s, pd, ps);
  k_bin_dst<<<NB, 256, 0, stream>>>(pd, bcur_d, deg_in, partials);
  k_scanp<<<1, 256, 0, stream>>>(partials, block_off, row_ptr);
  k_rowptr<<<(NN + 255) / 256, 256, 0, stream>>>(deg_in, block_off, row_ptr, norm_in);
  k_place<<<NB, 256, 0, stream>>>(pd, bcur_d, row_ptr, edge_src);
  k_bin_src<<<NB, 256, 0, stream>>>(ps, bcur_s, norm_in, norm_out, cw);
  k_xform<<<(NN + 63) / 64, 256, 0, stream>>>(feats, norm_out, W1, YP);
  k_agg<<<2048, 256, 0, stream>>>(YP, norm_in, cw, row_ptr, edge_src, b1, svec);
  k_final<<<1, 128, 0, stream>>>(svec, W2, b2, Wr, br, out);
}

// Round 8
// 269.207 us; speedup vs baseline: 1.1685x; 1.0483x over previous
//
#include <hip/hip_runtime.h>

// GCN 2-layer + mean-pool + readout.
// Algebra: aggregation is linear, so transform FIRST:
//   Y      = (norm_out ⊙ X) @ W1            (dense register-tiled GEMM, fp32)
//   h1[n]  = relu( norm_in[n] * sum_{e:dst=n} Y[src_e] + b1 )
//   out    = ((1/N) * sum_u c[u]*h1[u]) @ W2 + b2  @ Wr^T + br
//   c[u]   = norm_out[u] * sum_{e:src=u} norm_in[dst_e]
//
// No per-edge device-scope atomics anywhere (round-6 lesson: each one moves a
// 64B line at the coherence point). Two-level binning, now with a FUSED CSR
// builder: bucket b's CSR base = sum of bucket counts below b (nodes are
// bucket-contiguous), so no global scan pass is needed at all.
//   k_part   : partition edges into 49 buckets of 1024 nodes by dst AND src
//              (packed 26-bit entries); per-block LDS hist + bucket cursor
//              reservations (~38K global atomics total).
//   k_csr    : per bucket: LDS hist -> in-block base reduce -> local prefix
//              scan -> row_ptr/norm_in/cursors -> placement -> edge_src.
//   k_bin_src: per bucket: LDS deg_out + c_raw (norm_in gathers) -> norm_out, cw.
// Y fp32 in 8 column panels of 12 (2.4 MB, L2-resident per XCD); k_agg
// panel-per-XCD with wave-uniform degree branches.
//
// Pipeline: memset(1.5KB) -> k_part -> k_csr -> k_bin_src -> k_xform ->
//           k_agg -> k_final.   (7 dispatches)

constexpr int NN = 50000;
constexpr int NE = 800000;
constexpr int NB = 49;          // buckets of 1024 nodes (dst>>10 / src>>10)
constexpr int CAP = 24576;      // bucket capacity (mean 16384, +64 sigma)

// ws layout in 4-byte units:
constexpr int OFF_SVEC     = 0;        // float[256]  (zeroed)
constexpr int OFF_BCURD    = 256;      // int[64]     (zeroed)
constexpr int OFF_BCURS    = 320;      // int[64]     (zeroed)
constexpr int OFF_NORM_OUT = 384;      // float[50000]
constexpr int OFF_NORM_IN  = 50384;    // float[50000]
constexpr int OFF_CW       = 100384;   // float[50000]
constexpr int OFF_ROW_PTR  = 150384;   // int[50001] -> pad 200388
constexpr int OFF_EDGE_SRC = 200388;   // int[800000] -> 1000388
constexpr int OFF_PD       = 1000388;  // int[49*24576] (dead after k_csr)
constexpr int OFF_PS       = 2204612;  // int[49*24576] (dead after k_bin_src)
constexpr int OFF_YP       = 1000388;  // float[8][50000][12] aliases PD+PS
                                       // (k_xform runs after both are dead)
constexpr size_t ZERO_BYTES = (size_t)(OFF_NORM_OUT) * 4;   // svec + cursors

// One-pass dual partition (by dst bucket and by src bucket), 2048 edges/block.
__global__ __launch_bounds__(256)
void k_part(const int* __restrict__ src, const int* __restrict__ dst,
            int* __restrict__ bcur_d, int* __restrict__ bcur_s,
            int* __restrict__ pd, int* __restrict__ ps) {
  __shared__ int hd[64], hs[64], cd[64], cs[64];
  const int t = threadIdx.x;
  if (t < 64) { hd[t] = 0; hs[t] = 0; }
  __syncthreads();
  const int e0 = blockIdx.x * 2048;
  int s_[8], d_[8];
#pragma unroll
  for (int i = 0; i < 8; ++i) {
    int e = e0 + i * 256 + t;
    bool v = e < NE;
    s_[i] = v ? src[e] : -1;
    d_[i] = v ? dst[e] : -1;
    if (v) { atomicAdd(&hd[d_[i] >> 10], 1); atomicAdd(&hs[s_[i] >> 10], 1); }
  }
  __syncthreads();
  if (t < 64) {
    int c = hd[t];
    cd[t] = c ? (t * CAP + atomicAdd(&bcur_d[t], c)) : 0;
    c = hs[t];
    cs[t] = c ? (t * CAP + atomicAdd(&bcur_s[t], c)) : 0;
  }
  __syncthreads();
#pragma unroll
  for (int i = 0; i < 8; ++i) {
    if (s_[i] >= 0) {
      int pos = atomicAdd(&cd[d_[i] >> 10], 1);     // LDS
      pd[pos] = (s_[i] << 10) | (d_[i] & 1023);
      int pos2 = atomicAdd(&cs[s_[i] >> 10], 1);    // LDS
      ps[pos2] = (d_[i] << 10) | (s_[i] & 1023);
    }
  }
}

// Fused CSR builder per bucket: hist -> base (reduce over bucket counts) ->
// local prefix scan -> row_ptr + norm_in + cursors -> placement.
__global__ __launch_bounds__(256)
void k_csr(const int* __restrict__ pd, const int* __restrict__ bcur_d,
           int* __restrict__ row_ptr, float* __restrict__ norm_in,
           int* __restrict__ edge_src) {
  __shared__ int hist[1024], cur[1024], sc[256];
  __shared__ int carry_s;
  const int t = threadIdx.x, b = blockIdx.x;
  for (int i = t; i < 1024; i += 256) hist[i] = 0;
  __syncthreads();
  const int cnt = bcur_d[b];
  const int* pe = pd + b * CAP;
  for (int i = t; i < cnt; i += 256) atomicAdd(&hist[pe[i] & 1023], 1);

  // bucket base = sum of bucket counts below b
  sc[t] = (t < b) ? bcur_d[t] : 0;        // b <= 48 < 256
  __syncthreads();
  for (int s = 128; s > 0; s >>= 1) {
    if (t < s) sc[t] += sc[t + s];
    __syncthreads();
  }
  if (t == 0) carry_s = sc[0];
  __syncthreads();
  const int base0 = carry_s;

  // per-chunk Hillis-Steele scans with carried offset
  const int nb = b * 1024;
#pragma unroll
  for (int j = 0; j < 4; ++j) {
    int idx = j * 256 + t;
    int h = hist[idx];
    sc[t] = h;
    __syncthreads();
    for (int off = 1; off < 256; off <<= 1) {
      int u = (t >= off) ? sc[t - off] : 0;
      __syncthreads();
      sc[t] += u;
      __syncthreads();
    }
    int excl = carry_s + sc[t] - h;
    int n = nb + idx;
    if (n < NN) {
      row_ptr[n] = excl;
      norm_in[n] = 1.0f / sqrtf((float)max(h, 1));
    }
    cur[idx] = excl;
    __syncthreads();
    if (t == 255) carry_s = excl + h;
    __syncthreads();
  }
  if (b == NB - 1 && t == 0) row_ptr[NN] = base0 + cnt;

  // placement
  for (int i = t; i < cnt; i += 256) {
    int p = pe[i];
    int pos = atomicAdd(&cur[p & 1023], 1);   // LDS
    edge_src[pos] = p >> 10;
  }
}

// Per-bucket out-degree + c_raw (LDS atomics; norm_in gathers are L2-hot),
// emits norm_out and cw = norm_out * c_raw.
__global__ __launch_bounds__(256)
void k_bin_src(const int* __restrict__ ps, const int* __restrict__ bcur_s,
               const float* __restrict__ norm_in,
               float* __restrict__ norm_out, float* __restrict__ cw) {
  __shared__ int dout[1024];
  __shared__ float craw[1024];
  const int t = threadIdx.x, b = blockIdx.x, nb = b * 1024;
  for (int i = t; i < 1024; i += 256) { dout[i] = 0; craw[i] = 0.f; }
  __syncthreads();
  const int cnt = bcur_s[b];
  const int* pe = ps + b * CAP;
  for (int i = t; i < cnt; i += 256) {
    int p = pe[i];
    int sl = p & 1023, dg = p >> 10;
    atomicAdd(&dout[sl], 1);                  // LDS
    atomicAdd(&craw[sl], norm_in[dg]);        // LDS float add
  }
  __syncthreads();
  for (int i = t; i < 1024; i += 256) {
    int n = nb + i;
    if (n < NN) {
      float no = 1.0f / sqrtf((float)max(dout[i], 1));
      norm_out[n] = no;
      cw[n] = no * craw[i];
    }
  }
}

// Y = (norm_out ⊙ X) @ W1 — register-tiled GEMM, panel-layout fp32 output.
// One 64-node tile per block. X-tile staged TRANSPOSED in LDS (26 KB).
// Thread (tn=t&7, tm=t>>3) computes 2 nodes x 12 cols; tn IS the panel.
__global__ __launch_bounds__(256, 6)
void k_xform(const float* __restrict__ feats, const float* __restrict__ norm_out,
             const float* __restrict__ W1, float* __restrict__ YP) {
  __shared__ float XT[96][68];            // [k][node], pad 64->68
  const int t = threadIdx.x;
  const int nb = blockIdx.x * 64;         // tile base node

  const float4* f4 = (const float4*)feats;
#pragma unroll
  for (int i = 0; i < 6; ++i) {           // 6*256 = 1536 float4 = 64x96 floats
    int idx4 = i * 256 + t;
    int n = idx4 / 24;
    int kq = idx4 % 24;
    int ng = nb + n;
    float4 v = make_float4(0.f, 0.f, 0.f, 0.f);
    float no = 0.f;
    if (ng < NN) { v = f4[(size_t)ng * 24 + kq]; no = norm_out[ng]; }
    XT[kq * 4 + 0][n] = v.x * no;
    XT[kq * 4 + 1][n] = v.y * no;
    XT[kq * 4 + 2][n] = v.z * no;
    XT[kq * 4 + 3][n] = v.w * no;
  }
  __syncthreads();

  const int tn = t & 7;                   // panel / column chunk: cols 12*tn..
  const int tm = t >> 3;                  // node pair: nodes 2*tm, 2*tm+1
  float acc0[12], acc1[12];
#pragma unroll
  for (int c = 0; c < 12; ++c) { acc0[c] = 0.f; acc1[c] = 0.f; }

  const float4* W4 = (const float4*)(W1 + 12 * tn);   // row stride 24 float4
#pragma unroll 4
  for (int k = 0; k < 96; ++k) {
    float2 x = *(const float2*)&XT[k][2 * tm];
    float4 w0 = W4[k * 24 + 0];
    float4 w1 = W4[k * 24 + 1];
    float4 w2 = W4[k * 24 + 2];
    const float w[12] = {w0.x, w0.y, w0.z, w0.w, w1.x, w1.y, w1.z, w1.w,
                         w2.x, w2.y, w2.z, w2.w};
#pragma unroll
    for (int c = 0; c < 12; ++c) {
      acc0[c] = fmaf(x.x, w[c], acc0[c]);
      acc1[c] = fmaf(x.y, w[c], acc1[c]);
    }
  }

  int n0 = nb + 2 * tm;
  if (n0 < NN) {
    float4* yp = (float4*)(YP + ((size_t)tn * NN + n0) * 12);
    yp[0] = make_float4(acc0[0], acc0[1], acc0[2], acc0[3]);
    yp[1] = make_float4(acc0[4], acc0[5], acc0[6], acc0[7]);
    yp[2] = make_float4(acc0[8], acc0[9], acc0[10], acc0[11]);
  }
  if (n0 + 1 < NN) {
    float4* yp = (float4*)(YP + ((size_t)tn * NN + n0 + 1) * 12);
    yp[0] = make_float4(acc1[0], acc1[1], acc1[2], acc1[3]);
    yp[1] = make_float4(acc1[4], acc1[5], acc1[6], acc1[7]);
    yp[2] = make_float4(acc1[8], acc1[9], acc1[10], acc1[11]);
  }
}

// Panel-per-XCD CSR gather. Block b works on panel p = b%8 (lands on XCD p by
// round-robin dispatch), sweeping ALL nodes but only cols [12p,12p+12).
// Wave-uniform degree branches skip the masked second half for short rows.
__global__ __launch_bounds__(256, 8)
void k_agg(const float* __restrict__ YP,
           const float* __restrict__ norm_in, const float* __restrict__ cw,
           const int* __restrict__ row_ptr, const int* __restrict__ edge_src,
           const float* __restrict__ b1, float* __restrict__ svec) {
  __shared__ float red[12];
  const int tid = threadIdx.x;
  if (tid < 12) red[tid] = 0.f;
  __syncthreads();

  const int panel = blockIdx.x & 7;
  const int bp    = blockIdx.x >> 3;
  const int g = tid >> 5, l = tid & 31;
  const int ei = l / 3;
  const int q  = l - 3 * ei;
  const bool act = (l < 24);

  const float* Yp = YP + (size_t)panel * NN * 12;
  float4 b4 = make_float4(0.f, 0.f, 0.f, 0.f);
  if (l < 3) b4 = ((const float4*)b1)[3 * panel + l];

  float a0 = 0.f, a1 = 0.f, a2 = 0.f, a3 = 0.f;

  const int gid = bp * 8 + g;
  for (int n = gid; n < NN; n += 2048) {
    int e0 = row_ptr[n], e1 = row_ptr[n + 1];
    float v0 = 0.f, v1 = 0.f, v2 = 0.f, v3 = 0.f;
    for (int base = e0; base < e1; base += 32) {
      int idx = base + l;
      int es = (idx < e1) ? edge_src[idx] : 0;
      int cnt = min(32, e1 - base);
      int s0 = __shfl(es, ei, 32);
      float4 f0 = make_float4(0.f, 0.f, 0.f, 0.f);
      if (act && ei < cnt) f0 = *(const float4*)(Yp + (size_t)s0 * 12 + 4 * q);
      if (cnt > 8) {                       // wave-uniform branch
        int s1 = __shfl(es, 8 + ei, 32);
        float4 f1 = make_float4(0.f, 0.f, 0.f, 0.f);
        if (act && 8 + ei < cnt) f1 = *(const float4*)(Yp + (size_t)s1 * 12 + 4 * q);
        f0.x += f1.x; f0.y += f1.y; f0.z += f1.z; f0.w += f1.w;
      }
      if (cnt > 16) {                      // wave-uniform branch
        int s2 = __shfl(es, 16 + ei, 32);
        int s3 = __shfl(es, 24 + ei, 32);
        float4 f2 = make_float4(0.f, 0.f, 0.f, 0.f), f3 = f2;
        if (act && 16 + ei < cnt) f2 = *(const float4*)(Yp + (size_t)s2 * 12 + 4 * q);
        if (act && 24 + ei < cnt) f3 = *(const float4*)(Yp + (size_t)s3 * 12 + 4 * q);
        f0.x += f2.x + f3.x; f0.y += f2.y + f3.y;
        f0.z += f2.z + f3.z; f0.w += f2.w + f3.w;
      }
      v0 += f0.x; v1 += f0.y; v2 += f0.z; v3 += f0.w;
    }
    v0 += __shfl(v0, l + 12, 32); v1 += __shfl(v1, l + 12, 32);
    v2 += __shfl(v2, l + 12, 32); v3 += __shfl(v3, l + 12, 32);
    v0 += __shfl(v0, l + 6, 32);  v1 += __shfl(v1, l + 6, 32);
    v2 += __shfl(v2, l + 6, 32);  v3 += __shfl(v3, l + 6, 32);
    v0 += __shfl(v0, l + 3, 32);  v1 += __shfl(v1, l + 3, 32);
    v2 += __shfl(v2, l + 3, 32);  v3 += __shfl(v3, l + 3, 32);

    if (l < 3) {
      float ni = norm_in[n];
      float c  = cw[n];
      a0 += c * fmaxf(fmaf(ni, v0, b4.x), 0.f);
      a1 += c * fmaxf(fmaf(ni, v1, b4.y), 0.f);
      a2 += c * fmaxf(fmaf(ni, v2, b4.z), 0.f);
      a3 += c * fmaxf(fmaf(ni, v3, b4.w), 0.f);
    }
  }

  if (l < 3) {
    atomicAdd(&red[4 * l + 0], a0);
    atomicAdd(&red[4 * l + 1], a1);
    atomicAdd(&red[4 * l + 2], a2);
    atomicAdd(&red[4 * l + 3], a3);
  }
  __syncthreads();
  if (tid < 12) atomicAdd(&svec[12 * panel + tid], red[tid]);
}

// hg = (svec/N) @ W2 + b2 ; out = hg @ Wr^T + br
__global__ void k_final(const float* __restrict__ svec,
                        const float* __restrict__ W2, const float* __restrict__ b2,
                        const float* __restrict__ Wr, const float* __restrict__ br,
                        float* __restrict__ out) {
  __shared__ float hg[96];
  int j = threadIdx.x;
  if (j < 96) {
    float acc = b2[j];
    const float invN = 1.0f / (float)NN;
    for (int k = 0; k < 96; ++k)
      acc = fmaf(svec[k] * invN, W2[k * 96 + j], acc);
    hg[j] = acc;
  }
  __syncthreads();
  if (j < 8) {
    float acc = br[j];
    for (int k = 0; k < 96; ++k)
      acc = fmaf(hg[k], Wr[j * 96 + k], acc);
    out[j] = acc;
  }
}

extern "C" void kernel_launch(void* const* d_in, const int* in_sizes, int n_in,
                              void* d_out, int out_size, void* d_ws, size_t ws_size,
                              hipStream_t stream) {
  const float* feats = (const float*)d_in[0];
  const int*   src   = (const int*)d_in[1];
  const int*   dst   = (const int*)d_in[2];
  const float* W1    = (const float*)d_in[3];
  const float* b1    = (const float*)d_in[4];
  const float* W2    = (const float*)d_in[5];
  const float* b2    = (const float*)d_in[6];
  const float* Wr    = (const float*)d_in[7];
  const float* br    = (const float*)d_in[8];
  float* out = (float*)d_out;

  int*   wsi      = (int*)d_ws;
  float* wsf      = (float*)d_ws;
  float* svec     = wsf + OFF_SVEC;
  int*   bcur_d   = wsi + OFF_BCURD;
  int*   bcur_s   = wsi + OFF_BCURS;
  float* norm_out = wsf + OFF_NORM_OUT;
  float* norm_in  = wsf + OFF_NORM_IN;
  float* cw       = wsf + OFF_CW;
  int*   row_ptr  = wsi + OFF_ROW_PTR;
  int*   edge_src = wsi + OFF_EDGE_SRC;
  int*   pd       = wsi + OFF_PD;
  int*   ps       = wsi + OFF_PS;
  float* YP       = wsf + OFF_YP;        // aliases pd+ps (both dead by k_xform)

  hipMemsetAsync(d_ws, 0, ZERO_BYTES, stream);   // svec + bucket cursors

  k_part<<<(NE + 2047) / 2048, 256, 0, stream>>>(src, dst, bcur_d, bcur_s, pd, ps);
  k_csr<<<NB, 256, 0, stream>>>(pd, bcur_d, row_ptr, norm_in, edge_src);
  k_bin_src<<<NB, 256, 0, stream>>>(ps, bcur_s, norm_in, norm_out, cw);
  k_xform<<<(NN + 63) / 64, 256, 0, stream>>>(feats, norm_out, W1, YP);
  k_agg<<<2048, 256, 0, stream>>>(YP, norm_in, cw, row_ptr, edge_src, b1, svec);
  k_final<<<1, 128, 0, stream>>>(svec, W2, b2, Wr, br, out);
}

// Round 9
// 226.324 us; speedup vs baseline: 1.3899x; 1.1895x over previous
//
#include <hip/hip_runtime.h>

// GCN 2-layer + mean-pool + readout.
// Algebra: aggregation is linear, so transform FIRST:
//   Y      = (norm_out ⊙ X) @ W1            (dense register-tiled GEMM, fp32)
//   h1[n]  = relu( norm_in[n] * sum_{e:dst=n} Y[src_e] + b1 )
//   out    = ((1/N) * sum_u c[u]*h1[u]) @ W2 + b2  @ Wr^T + br
//   c[u]   = norm_out[u] * sum_{e:src=u} norm_in[dst_e]
//
// No per-edge device-scope atomics (each costs a 64B line move at the
// coherence point). Two-level binning with 196 buckets of 256 nodes:
//   k_part   : partition edges by dst AND src bucket (packed (id<<8)|local).
//              Bucket-cursor reservations are LINE-PADDED (stride 16) so the
//              per-bucket reservation streams are line-parallel.
//   k_csr    : per bucket (196 blocks): LDS hist -> base reduce -> 256-scan ->
//              row_ptr/norm_in/cursors -> placement -> ushort edge_src.
//   k_bin_src: per bucket: LDS deg_out + c_raw -> norm_out, cw.
// Y fp32 in 8 column panels of 12 (2.4 MB, L2-resident per XCD). k_agg:
// panel-per-XCD gather with NODE-PAIR ILP (two independent gather chains).
//
// Pipeline: memset(26KB) -> k_part -> k_csr -> k_bin_src -> k_xform ->
//           k_agg -> k_final.   (7 dispatches)

constexpr int NN = 50000;
constexpr int NE = 800000;
constexpr int NB = 196;         // buckets of 256 nodes
constexpr int CAP = 6144;       // bucket capacity (mean 4082, +32 sigma)

// ws layout in 4-byte units:
constexpr int OFF_SVEC     = 0;        // float[256]  (zeroed)
constexpr int OFF_BCURD    = 256;      // int[196*16] line-padded (zeroed)
constexpr int OFF_BCURS    = 3392;     // int[196*16] line-padded (zeroed)
constexpr int OFF_NORM_OUT = 6528;     // float[50000]
constexpr int OFF_NORM_IN  = 56528;    // float[50000]
constexpr int OFF_CW       = 106528;   // float[50000]
constexpr int OFF_ROW_PTR  = 156528;   // int[50001] -> pad 206532
constexpr int OFF_EDGE_SRC = 206532;   // ushort[800000] = 400000 ints -> 606532
constexpr int OFF_PD       = 606532;   // int[196*6144] (dead after k_csr)
constexpr int OFF_PS       = 1810756;  // int[196*6144] (dead after k_bin_src)
constexpr int OFF_YP       = 606532;   // float[8][50000][12] aliases PD+PS
                                       // (k_xform runs after both are dead)
constexpr size_t ZERO_BYTES = (size_t)(OFF_NORM_OUT) * 4;   // svec + cursors

// One-pass dual partition (by dst bucket and by src bucket), 2048 edges/block.
__global__ __launch_bounds__(256)
void k_part(const int* __restrict__ src, const int* __restrict__ dst,
            int* __restrict__ bcur_d, int* __restrict__ bcur_s,
            int* __restrict__ pd, int* __restrict__ ps) {
  __shared__ int hd[256], hs[256], cd[256], cs[256];
  const int t = threadIdx.x;
  hd[t] = 0; hs[t] = 0;
  __syncthreads();
  const int e0 = blockIdx.x * 2048;
  int s_[8], d_[8];
#pragma unroll
  for (int i = 0; i < 8; ++i) {
    int e = e0 + i * 256 + t;
    bool v = e < NE;
    s_[i] = v ? src[e] : -1;
    d_[i] = v ? dst[e] : -1;
    if (v) { atomicAdd(&hd[d_[i] >> 8], 1); atomicAdd(&hs[s_[i] >> 8], 1); }
  }
  __syncthreads();
  if (t < NB) {
    int c = hd[t];
    cd[t] = c ? (t * CAP + atomicAdd(&bcur_d[t * 16], c)) : 0;  // padded cursor
    c = hs[t];
    cs[t] = c ? (t * CAP + atomicAdd(&bcur_s[t * 16], c)) : 0;
  }
  __syncthreads();
#pragma unroll
  for (int i = 0; i < 8; ++i) {
    if (s_[i] >= 0) {
      int pos = atomicAdd(&cd[d_[i] >> 8], 1);      // LDS
      pd[pos] = (s_[i] << 8) | (d_[i] & 255);
      int pos2 = atomicAdd(&cs[s_[i] >> 8], 1);     // LDS
      ps[pos2] = (d_[i] << 8) | (s_[i] & 255);
    }
  }
}

// Fused CSR builder per bucket: hist -> base (reduce over bucket counts) ->
// 256-wide prefix scan -> row_ptr + norm_in + cursors -> placement.
__global__ __launch_bounds__(256)
void k_csr(const int* __restrict__ pd, const int* __restrict__ bcur_d,
           int* __restrict__ row_ptr, float* __restrict__ norm_in,
           unsigned short* __restrict__ edge_src) {
  __shared__ int hist[256], cur[256], sc[256];
  const int t = threadIdx.x, b = blockIdx.x;
  hist[t] = 0;
  __syncthreads();
  const int cnt = bcur_d[b * 16];
  const int* pe = pd + b * CAP;
  for (int i = t; i < cnt; i += 256) atomicAdd(&hist[pe[i] & 255], 1);

  // bucket base = sum of bucket counts below b
  sc[t] = (t < b) ? bcur_d[t * 16] : 0;     // b <= 195 < 256
  __syncthreads();
  for (int s = 128; s > 0; s >>= 1) {
    if (t < s) sc[t] += sc[t + s];
    __syncthreads();
  }
  const int base0 = sc[0];
  __syncthreads();

  // single 256-wide Hillis-Steele scan of hist
  int h = hist[t];
  sc[t] = h;
  __syncthreads();
  for (int off = 1; off < 256; off <<= 1) {
    int u = (t >= off) ? sc[t - off] : 0;
    __syncthreads();
    sc[t] += u;
    __syncthreads();
  }
  int excl = base0 + sc[t] - h;
  int n = b * 256 + t;
  if (n < NN) {
    row_ptr[n] = excl;
    norm_in[n] = 1.0f / sqrtf((float)max(h, 1));
  }
  cur[t] = excl;
  __syncthreads();
  if (b == NB - 1 && t == 0) row_ptr[NN] = base0 + cnt;

  // placement (ushort: node ids < 65536)
  for (int i = t; i < cnt; i += 256) {
    int p = pe[i];
    int pos = atomicAdd(&cur[p & 255], 1);   // LDS
    edge_src[pos] = (unsigned short)(p >> 8);
  }
}

// Per-bucket out-degree + c_raw (LDS atomics; norm_in gathers are L2-hot),
// emits norm_out and cw = norm_out * c_raw.
__global__ __launch_bounds__(256)
void k_bin_src(const int* __restrict__ ps, const int* __restrict__ bcur_s,
               const float* __restrict__ norm_in,
               float* __restrict__ norm_out, float* __restrict__ cw) {
  __shared__ int dout[256];
  __shared__ float craw[256];
  const int t = threadIdx.x, b = blockIdx.x;
  dout[t] = 0; craw[t] = 0.f;
  __syncthreads();
  const int cnt = bcur_s[b * 16];
  const int* pe = ps + b * CAP;
  for (int i = t; i < cnt; i += 256) {
    int p = pe[i];
    atomicAdd(&dout[p & 255], 1);             // LDS
    atomicAdd(&craw[p & 255], norm_in[p >> 8]);  // LDS float add
  }
  __syncthreads();
  int n = b * 256 + t;
  if (n < NN) {
    float no = 1.0f / sqrtf((float)max(dout[t], 1));
    norm_out[n] = no;
    cw[n] = no * craw[t];
  }
}

// Y = (norm_out ⊙ X) @ W1 — register-tiled GEMM, panel-layout fp32 output.
__global__ __launch_bounds__(256, 6)
void k_xform(const float* __restrict__ feats, const float* __restrict__ norm_out,
             const float* __restrict__ W1, float* __restrict__ YP) {
  __shared__ float XT[96][68];            // [k][node], pad 64->68
  const int t = threadIdx.x;
  const int nb = blockIdx.x * 64;         // tile base node

  const float4* f4 = (const float4*)feats;
#pragma unroll
  for (int i = 0; i < 6; ++i) {           // 6*256 = 1536 float4 = 64x96 floats
    int idx4 = i * 256 + t;
    int n = idx4 / 24;
    int kq = idx4 % 24;
    int ng = nb + n;
    float4 v = make_float4(0.f, 0.f, 0.f, 0.f);
    float no = 0.f;
    if (ng < NN) { v = f4[(size_t)ng * 24 + kq]; no = norm_out[ng]; }
    XT[kq * 4 + 0][n] = v.x * no;
    XT[kq * 4 + 1][n] = v.y * no;
    XT[kq * 4 + 2][n] = v.z * no;
    XT[kq * 4 + 3][n] = v.w * no;
  }
  __syncthreads();

  const int tn = t & 7;                   // panel / column chunk: cols 12*tn..
  const int tm = t >> 3;                  // node pair: nodes 2*tm, 2*tm+1
  float acc0[12], acc1[12];
#pragma unroll
  for (int c = 0; c < 12; ++c) { acc0[c] = 0.f; acc1[c] = 0.f; }

  const float4* W4 = (const float4*)(W1 + 12 * tn);   // row stride 24 float4
#pragma unroll 4
  for (int k = 0; k < 96; ++k) {
    float2 x = *(const float2*)&XT[k][2 * tm];
    float4 w0 = W4[k * 24 + 0];
    float4 w1 = W4[k * 24 + 1];
    float4 w2 = W4[k * 24 + 2];
    const float w[12] = {w0.x, w0.y, w0.z, w0.w, w1.x, w1.y, w1.z, w1.w,
                         w2.x, w2.y, w2.z, w2.w};
#pragma unroll
    for (int c = 0; c < 12; ++c) {
      acc0[c] = fmaf(x.x, w[c], acc0[c]);
      acc1[c] = fmaf(x.y, w[c], acc1[c]);
    }
  }

  int n0 = nb + 2 * tm;
  if (n0 < NN) {
    float4* yp = (float4*)(YP + ((size_t)tn * NN + n0) * 12);
    yp[0] = make_float4(acc0[0], acc0[1], acc0[2], acc0[3]);
    yp[1] = make_float4(acc0[4], acc0[5], acc0[6], acc0[7]);
    yp[2] = make_float4(acc0[8], acc0[9], acc0[10], acc0[11]);
  }
  if (n0 + 1 < NN) {
    float4* yp = (float4*)(YP + ((size_t)tn * NN + n0 + 1) * 12);
    yp[0] = make_float4(acc1[0], acc1[1], acc1[2], acc1[3]);
    yp[1] = make_float4(acc1[4], acc1[5], acc1[6], acc1[7]);
    yp[2] = make_float4(acc1[8], acc1[9], acc1[10], acc1[11]);
  }
}

// Panel-per-XCD CSR gather with NODE-PAIR ILP: each 32-lane group runs two
// independent gather chains (nodes n and n+2048) to hide L2 latency.
__global__ __launch_bounds__(256, 6)
void k_agg(const float* __restrict__ YP,
           const float* __restrict__ norm_in, const float* __restrict__ cw,
           const int* __restrict__ row_ptr, const unsigned short* __restrict__ edge_src,
           const float* __restrict__ b1, float* __restrict__ svec) {
  __shared__ float red[12];
  const int tid = threadIdx.x;
  if (tid < 12) red[tid] = 0.f;
  __syncthreads();

  const int panel = blockIdx.x & 7;
  const int bp    = blockIdx.x >> 3;
  const int g = tid >> 5, l = tid & 31;
  const int ei = l / 3;
  const int q  = l - 3 * ei;
  const bool act = (l < 24);

  const float* Yp = YP + (size_t)panel * NN * 12;
  float4 b4 = make_float4(0.f, 0.f, 0.f, 0.f);
  if (l < 3) b4 = ((const float4*)b1)[3 * panel + l];

  float a0 = 0.f, a1 = 0.f, a2 = 0.f, a3 = 0.f;

  const int gid = bp * 8 + g;
  for (int n = gid; n < NN; n += 4096) {
    const int m = n + 2048;
    const bool hb = (m < NN);
    int e1a = row_ptr[n + 1], basea = row_ptr[n];
    int e1b = 0, baseb = 0;
    if (hb) { e1b = row_ptr[m + 1]; baseb = row_ptr[m]; }
    float va0 = 0.f, va1 = 0.f, va2 = 0.f, va3 = 0.f;
    float vb0 = 0.f, vb1 = 0.f, vb2 = 0.f, vb3 = 0.f;

    while (basea < e1a || baseb < e1b) {
      int cnta = min(32, e1a - basea);
      int cntb = min(32, e1b - baseb);
      int esa = 0, esb = 0;
      if (basea + l < e1a) esa = edge_src[basea + l];
      if (baseb + l < e1b) esb = edge_src[baseb + l];

      if (cnta > 0) {
        int s0 = __shfl(esa, ei, 32);
        float4 f0 = make_float4(0.f, 0.f, 0.f, 0.f);
        if (act && ei < cnta) f0 = *(const float4*)(Yp + (size_t)s0 * 12 + 4 * q);
        if (cnta > 8) {
          int s1 = __shfl(esa, 8 + ei, 32);
          float4 f1 = make_float4(0.f, 0.f, 0.f, 0.f);
          if (act && 8 + ei < cnta) f1 = *(const float4*)(Yp + (size_t)s1 * 12 + 4 * q);
          f0.x += f1.x; f0.y += f1.y; f0.z += f1.z; f0.w += f1.w;
        }
        if (cnta > 16) {
          int s2 = __shfl(esa, 16 + ei, 32);
          int s3 = __shfl(esa, 24 + ei, 32);
          float4 f2 = make_float4(0.f, 0.f, 0.f, 0.f), f3 = f2;
          if (act && 16 + ei < cnta) f2 = *(const float4*)(Yp + (size_t)s2 * 12 + 4 * q);
          if (act && 24 + ei < cnta) f3 = *(const float4*)(Yp + (size_t)s3 * 12 + 4 * q);
          f0.x += f2.x + f3.x; f0.y += f2.y + f3.y;
          f0.z += f2.z + f3.z; f0.w += f2.w + f3.w;
        }
        va0 += f0.x; va1 += f0.y; va2 += f0.z; va3 += f0.w;
      }
      if (cntb > 0) {
        int s0 = __shfl(esb, ei, 32);
        float4 f0 = make_float4(0.f, 0.f, 0.f, 0.f);
        if (act && ei < cntb) f0 = *(const float4*)(Yp + (size_t)s0 * 12 + 4 * q);
        if (cntb > 8) {
          int s1 = __shfl(esb, 8 + ei, 32);
          float4 f1 = make_float4(0.f, 0.f, 0.f, 0.f);
          if (act && 8 + ei < cntb) f1 = *(const float4*)(Yp + (size_t)s1 * 12 + 4 * q);
          f0.x += f1.x; f0.y += f1.y; f0.z += f1.z; f0.w += f1.w;
        }
        if (cntb > 16) {
          int s2 = __shfl(esb, 16 + ei, 32);
          int s3 = __shfl(esb, 24 + ei, 32);
          float4 f2 = make_float4(0.f, 0.f, 0.f, 0.f), f3 = f2;
          if (act && 16 + ei < cntb) f2 = *(const float4*)(Yp + (size_t)s2 * 12 + 4 * q);
          if (act && 24 + ei < cntb) f3 = *(const float4*)(Yp + (size_t)s3 * 12 + 4 * q);
          f0.x += f2.x + f3.x; f0.y += f2.y + f3.y;
          f0.z += f2.z + f3.z; f0.w += f2.w + f3.w;
        }
        vb0 += f0.x; vb1 += f0.y; vb2 += f0.z; vb3 += f0.w;
      }
      basea += 32; baseb += 32;
    }

    // reduce across the 8 edge slots (lanes 3k+q -> lanes 0..2)
    va0 += __shfl(va0, l + 12, 32); va1 += __shfl(va1, l + 12, 32);
    va2 += __shfl(va2, l + 12, 32); va3 += __shfl(va3, l + 12, 32);
    va0 += __shfl(va0, l + 6, 32);  va1 += __shfl(va1, l + 6, 32);
    va2 += __shfl(va2, l + 6, 32);  va3 += __shfl(va3, l + 6, 32);
    va0 += __shfl(va0, l + 3, 32);  va1 += __shfl(va1, l + 3, 32);
    va2 += __shfl(va2, l + 3, 32);  va3 += __shfl(va3, l + 3, 32);

    vb0 += __shfl(vb0, l + 12, 32); vb1 += __shfl(vb1, l + 12, 32);
    vb2 += __shfl(vb2, l + 12, 32); vb3 += __shfl(vb3, l + 12, 32);
    vb0 += __shfl(vb0, l + 6, 32);  vb1 += __shfl(vb1, l + 6, 32);
    vb2 += __shfl(vb2, l + 6, 32);  vb3 += __shfl(vb3, l + 6, 32);
    vb0 += __shfl(vb0, l + 3, 32);  vb1 += __shfl(vb1, l + 3, 32);
    vb2 += __shfl(vb2, l + 3, 32);  vb3 += __shfl(vb3, l + 3, 32);

    if (l < 3) {
      float ni = norm_in[n], c = cw[n];
      a0 += c * fmaxf(fmaf(ni, va0, b4.x), 0.f);
      a1 += c * fmaxf(fmaf(ni, va1, b4.y), 0.f);
      a2 += c * fmaxf(fmaf(ni, va2, b4.z), 0.f);
      a3 += c * fmaxf(fmaf(ni, va3, b4.w), 0.f);
      if (hb) {
        float nib = norm_in[m], cb = cw[m];
        a0 += cb * fmaxf(fmaf(nib, vb0, b4.x), 0.f);
        a1 += cb * fmaxf(fmaf(nib, vb1, b4.y), 0.f);
        a2 += cb * fmaxf(fmaf(nib, vb2, b4.z), 0.f);
        a3 += cb * fmaxf(fmaf(nib, vb3, b4.w), 0.f);
      }
    }
  }

  if (l < 3) {
    atomicAdd(&red[4 * l + 0], a0);
    atomicAdd(&red[4 * l + 1], a1);
    atomicAdd(&red[4 * l + 2], a2);
    atomicAdd(&red[4 * l + 3], a3);
  }
  __syncthreads();
  if (tid < 12) atomicAdd(&svec[12 * panel + tid], red[tid]);
}

// hg = (svec/N) @ W2 + b2 ; out = hg @ Wr^T + br
__global__ void k_final(const float* __restrict__ svec,
                        const float* __restrict__ W2, const float* __restrict__ b2,
                        const float* __restrict__ Wr, const float* __restrict__ br,
                        float* __restrict__ out) {
  __shared__ float hg[96];
  int j = threadIdx.x;
  if (j < 96) {
    float acc = b2[j];
    const float invN = 1.0f / (float)NN;
    for (int k = 0; k < 96; ++k)
      acc = fmaf(svec[k] * invN, W2[k * 96 + j], acc);
    hg[j] = acc;
  }
  __syncthreads();
  if (j < 8) {
    float acc = br[j];
    for (int k = 0; k < 96; ++k)
      acc = fmaf(hg[k], Wr[j * 96 + k], acc);
    out[j] = acc;
  }
}

extern "C" void kernel_launch(void* const* d_in, const int* in_sizes, int n_in,
                              void* d_out, int out_size, void* d_ws, size_t ws_size,
                              hipStream_t stream) {
  const float* feats = (const float*)d_in[0];
  const int*   src   = (const int*)d_in[1];
  const int*   dst   = (const int*)d_in[2];
  const float* W1    = (const float*)d_in[3];
  const float* b1    = (const float*)d_in[4];
  const float* W2    = (const float*)d_in[5];
  const float* b2    = (const float*)d_in[6];
  const float* Wr    = (const float*)d_in[7];
  const float* br    = (const float*)d_in[8];
  float* out = (float*)d_out;

  int*   wsi      = (int*)d_ws;
  float* wsf      = (float*)d_ws;
  float* svec     = wsf + OFF_SVEC;
  int*   bcur_d   = wsi + OFF_BCURD;
  int*   bcur_s   = wsi + OFF_BCURS;
  float* norm_out = wsf + OFF_NORM_OUT;
  float* norm_in  = wsf + OFF_NORM_IN;
  float* cw       = wsf + OFF_CW;
  int*   row_ptr  = wsi + OFF_ROW_PTR;
  unsigned short* edge_src = (unsigned short*)(wsi + OFF_EDGE_SRC);
  int*   pd       = wsi + OFF_PD;
  int*   ps       = wsi + OFF_PS;
  float* YP       = wsf + OFF_YP;        // aliases pd+ps (both dead by k_xform)

  hipMemsetAsync(d_ws, 0, ZERO_BYTES, stream);   // svec + padded cursors

  k_part<<<(NE + 2047) / 2048, 256, 0, stream>>>(src, dst, bcur_d, bcur_s, pd, ps);
  k_csr<<<NB, 256, 0, stream>>>(pd, bcur_d, row_ptr, norm_in, edge_src);
  k_bin_src<<<NB, 256, 0, stream>>>(ps, bcur_s, norm_in, norm_out, cw);
  k_xform<<<(NN + 63) / 64, 256, 0, stream>>>(feats, norm_out, W1, YP);
  k_agg<<<2048, 256, 0, stream>>>(YP, norm_in, cw, row_ptr, edge_src, b1, svec);
  k_final<<<1, 128, 0, stream>>>(svec, W2, b2, Wr, br, out);
}

// Round 10
// 219.540 us; speedup vs baseline: 1.4329x; 1.0309x over previous
//
#include <hip/hip_runtime.h>

// GCN 2-layer + mean-pool + readout.
// Algebra: aggregation is linear, so transform FIRST:
//   Y      = (norm_out ⊙ X) @ W1            (dense register-tiled GEMM, fp32)
//   h1[n]  = relu( norm_in[n] * sum_{e:dst=n} Y[src_e] + b1 )
//   out    = ((1/N) * sum_u c[u]*h1[u]) @ W2 + b2  @ Wr^T + br
//   c[u]   = norm_out[u] * sum_{e:src=u} norm_in[dst_e]
//
// No per-edge device-scope atomics (each moves a 64B line at the coherence
// point). Two-level binning, 196 buckets of 256 nodes:
//   k_part   : dual partition by dst/src bucket. LDS REORDER-THEN-FLUSH:
//              entries placed bucket-contiguously in LDS, then written out
//              linearly so consecutive lanes hit consecutive addresses
//              (round-9 lesson: direct scattered writes = 64 lines/wave).
//   k_csr    : per bucket: stage entries ONCE in LDS -> hist -> base reduce ->
//              256-scan -> row_ptr/norm_in -> placement -> ushort edge_src.
//   k_bin_src: per bucket: LDS deg_out + c_raw -> norm_out, cw.
// Y fp32 in 8 column panels of 12 (2.4 MB, L2-resident per XCD). k_agg is at
// the L2 16B-request-rate roofline (~59us): 3 float4/edge/panel is invariant.
//
// Pipeline: memset(26KB) -> k_part -> k_csr -> k_bin_src -> k_xform ->
//           k_agg -> k_final.   (7 dispatches)

constexpr int NN = 50000;
constexpr int NE = 800000;
constexpr int NB = 196;         // buckets of 256 nodes
constexpr int CAP = 6144;       // bucket capacity (mean 4082, +32 sigma)

// ws layout in 4-byte units:
constexpr int OFF_SVEC     = 0;        // float[256]  (zeroed)
constexpr int OFF_BCURD    = 256;      // int[196*16] line-padded (zeroed)
constexpr int OFF_BCURS    = 3392;     // int[196*16] line-padded (zeroed)
constexpr int OFF_NORM_OUT = 6528;     // float[50000]
constexpr int OFF_NORM_IN  = 56528;    // float[50000]
constexpr int OFF_CW       = 106528;   // float[50000]
constexpr int OFF_ROW_PTR  = 156528;   // int[50001] -> pad 206532
constexpr int OFF_EDGE_SRC = 206532;   // ushort[800000] = 400000 ints -> 606532
constexpr int OFF_PD       = 606532;   // int[196*6144] (dead after k_csr)
constexpr int OFF_PS       = 1810756;  // int[196*6144] (dead after k_bin_src)
constexpr int OFF_YP       = 606532;   // float[8][50000][12] aliases PD+PS
constexpr size_t ZERO_BYTES = (size_t)(OFF_NORM_OUT) * 4;   // svec + cursors

// Dual partition with LDS reorder-then-flush (coalesced bucket-run writes).
__global__ __launch_bounds__(256)
void k_part(const int* __restrict__ src, const int* __restrict__ dst,
            int* __restrict__ bcur_d, int* __restrict__ bcur_s,
            int* __restrict__ pd, int* __restrict__ ps) {
  __shared__ int hd[256], hs[256], gd[256], gs[256];
  __shared__ int ldx[256], cur[256], scn[256];
  __shared__ int stage[2048];
  __shared__ unsigned char stageB[2048];
  const int t = threadIdx.x;
  hd[t] = 0; hs[t] = 0;
  __syncthreads();
  const int e0 = blockIdx.x * 2048;
  int s_[8], d_[8];
#pragma unroll
  for (int i = 0; i < 8; ++i) {
    int e = e0 + i * 256 + t;
    bool v = e < NE;
    s_[i] = v ? src[e] : -1;
    d_[i] = v ? dst[e] : -1;
    if (v) { atomicAdd(&hd[d_[i] >> 8], 1); atomicAdd(&hs[s_[i] >> 8], 1); }
  }
  __syncthreads();
  if (t < NB) {
    int c = hd[t];
    gd[t] = c ? (t * CAP + atomicAdd(&bcur_d[t * 16], c)) : 0;
    c = hs[t];
    gs[t] = c ? (t * CAP + atomicAdd(&bcur_s[t * 16], c)) : 0;
  }

  // ---- dst partition: scan -> LDS place -> linear flush ----
  scn[t] = hd[t];
  __syncthreads();
  for (int off = 1; off < 256; off <<= 1) {
    int u = (t >= off) ? scn[t - off] : 0;
    __syncthreads();
    scn[t] += u;
    __syncthreads();
  }
  ldx[t] = scn[t] - hd[t];
  cur[t] = scn[t] - hd[t];
  const int totd = scn[255];
  __syncthreads();
#pragma unroll
  for (int i = 0; i < 8; ++i) {
    if (d_[i] >= 0) {
      int B = d_[i] >> 8;
      int p = atomicAdd(&cur[B], 1);             // LDS
      stage[p] = (s_[i] << 8) | (d_[i] & 255);
      stageB[p] = (unsigned char)B;
    }
  }
  __syncthreads();
  for (int j = t; j < totd; j += 256) {          // coalesced within runs
    int B = stageB[j];
    pd[gd[B] + (j - ldx[B])] = stage[j];
  }
  __syncthreads();

  // ---- src partition: same machinery, reusing stage ----
  scn[t] = hs[t];
  __syncthreads();
  for (int off = 1; off < 256; off <<= 1) {
    int u = (t >= off) ? scn[t - off] : 0;
    __syncthreads();
    scn[t] += u;
    __syncthreads();
  }
  ldx[t] = scn[t] - hs[t];
  cur[t] = scn[t] - hs[t];
  const int tots = scn[255];
  __syncthreads();
#pragma unroll
  for (int i = 0; i < 8; ++i) {
    if (s_[i] >= 0) {
      int B = s_[i] >> 8;
      int p = atomicAdd(&cur[B], 1);             // LDS
      stage[p] = (d_[i] << 8) | (s_[i] & 255);
      stageB[p] = (unsigned char)B;
    }
  }
  __syncthreads();
  for (int j = t; j < tots; j += 256) {
    int B = stageB[j];
    ps[gs[B] + (j - ldx[B])] = stage[j];
  }
}

// Fused CSR builder per bucket: stage entries in LDS ONCE -> hist -> base
// reduce -> 256-wide scan -> row_ptr + norm_in + cursors -> placement.
__global__ __launch_bounds__(256)
void k_csr(const int* __restrict__ pd, const int* __restrict__ bcur_d,
           int* __restrict__ row_ptr, float* __restrict__ norm_in,
           unsigned short* __restrict__ edge_src) {
  __shared__ int pe_s[CAP];                      // 24KB bucket staging
  __shared__ int hist[256], cur[256], sc[256];
  const int t = threadIdx.x, b = blockIdx.x;
  hist[t] = 0;
  __syncthreads();
  const int cnt = bcur_d[b * 16];
  const int* pe = pd + b * CAP;
  for (int i = t; i < cnt; i += 256) {
    int p = pe[i];                               // single coalesced global read
    pe_s[i] = p;
    atomicAdd(&hist[p & 255], 1);
  }

  // bucket base = sum of bucket counts below b
  sc[t] = (t < b) ? bcur_d[t * 16] : 0;          // b <= 195 < 256
  __syncthreads();
  for (int s = 128; s > 0; s >>= 1) {
    if (t < s) sc[t] += sc[t + s];
    __syncthreads();
  }
  const int base0 = sc[0];
  __syncthreads();

  // 256-wide Hillis-Steele scan of hist
  int h = hist[t];
  sc[t] = h;
  __syncthreads();
  for (int off = 1; off < 256; off <<= 1) {
    int u = (t >= off) ? sc[t - off] : 0;
    __syncthreads();
    sc[t] += u;
    __syncthreads();
  }
  int excl = base0 + sc[t] - h;
  int n = b * 256 + t;
  if (n < NN) {
    row_ptr[n] = excl;
    norm_in[n] = 1.0f / sqrtf((float)max(h, 1));
  }
  cur[t] = excl;
  __syncthreads();
  if (b == NB - 1 && t == 0) row_ptr[NN] = base0 + cnt;

  // placement from LDS (ushort: node ids < 65536)
  for (int i = t; i < cnt; i += 256) {
    int p = pe_s[i];
    int pos = atomicAdd(&cur[p & 255], 1);       // LDS
    edge_src[pos] = (unsigned short)(p >> 8);
  }
}

// Per-bucket out-degree + c_raw (LDS atomics; norm_in gathers are L2-hot),
// emits norm_out and cw = norm_out * c_raw.
__global__ __launch_bounds__(256)
void k_bin_src(const int* __restrict__ ps, const int* __restrict__ bcur_s,
               const float* __restrict__ norm_in,
               float* __restrict__ norm_out, float* __restrict__ cw) {
  __shared__ int dout[256];
  __shared__ float craw[256];
  const int t = threadIdx.x, b = blockIdx.x;
  dout[t] = 0; craw[t] = 0.f;
  __syncthreads();
  const int cnt = bcur_s[b * 16];
  const int* pe = ps + b * CAP;
  for (int i = t; i < cnt; i += 256) {
    int p = pe[i];
    atomicAdd(&dout[p & 255], 1);                // LDS
    atomicAdd(&craw[p & 255], norm_in[p >> 8]);  // LDS float add
  }
  __syncthreads();
  int n = b * 256 + t;
  if (n < NN) {
    float no = 1.0f / sqrtf((float)max(dout[t], 1));
    norm_out[n] = no;
    cw[n] = no * craw[t];
  }
}

// Y = (norm_out ⊙ X) @ W1 — register-tiled GEMM, panel-layout fp32 output.
__global__ __launch_bounds__(256, 6)
void k_xform(const float* __restrict__ feats, const float* __restrict__ norm_out,
             const float* __restrict__ W1, float* __restrict__ YP) {
  __shared__ float XT[96][68];            // [k][node], pad 64->68
  const int t = threadIdx.x;
  const int nb = blockIdx.x * 64;         // tile base node

  const float4* f4 = (const float4*)feats;
#pragma unroll
  for (int i = 0; i < 6; ++i) {           // 6*256 = 1536 float4 = 64x96 floats
    int idx4 = i * 256 + t;
    int n = idx4 / 24;
    int kq = idx4 % 24;
    int ng = nb + n;
    float4 v = make_float4(0.f, 0.f, 0.f, 0.f);
    float no = 0.f;
    if (ng < NN) { v = f4[(size_t)ng * 24 + kq]; no = norm_out[ng]; }
    XT[kq * 4 + 0][n] = v.x * no;
    XT[kq * 4 + 1][n] = v.y * no;
    XT[kq * 4 + 2][n] = v.z * no;
    XT[kq * 4 + 3][n] = v.w * no;
  }
  __syncthreads();

  const int tn = t & 7;                   // panel / column chunk: cols 12*tn..
  const int tm = t >> 3;                  // node pair: nodes 2*tm, 2*tm+1
  float acc0[12], acc1[12];
#pragma unroll
  for (int c = 0; c < 12; ++c) { acc0[c] = 0.f; acc1[c] = 0.f; }

  const float4* W4 = (const float4*)(W1 + 12 * tn);   // row stride 24 float4
#pragma unroll 4
  for (int k = 0; k < 96; ++k) {
    float2 x = *(const float2*)&XT[k][2 * tm];
    float4 w0 = W4[k * 24 + 0];
    float4 w1 = W4[k * 24 + 1];
    float4 w2 = W4[k * 24 + 2];
    const float w[12] = {w0.x, w0.y, w0.z, w0.w, w1.x, w1.y, w1.z, w1.w,
                         w2.x, w2.y, w2.z, w2.w};
#pragma unroll
    for (int c = 0; c < 12; ++c) {
      acc0[c] = fmaf(x.x, w[c], acc0[c]);
      acc1[c] = fmaf(x.y, w[c], acc1[c]);
    }
  }

  int n0 = nb + 2 * tm;
  if (n0 < NN) {
    float4* yp = (float4*)(YP + ((size_t)tn * NN + n0) * 12);
    yp[0] = make_float4(acc0[0], acc0[1], acc0[2], acc0[3]);
    yp[1] = make_float4(acc0[4], acc0[5], acc0[6], acc0[7]);
    yp[2] = make_float4(acc0[8], acc0[9], acc0[10], acc0[11]);
  }
  if (n0 + 1 < NN) {
    float4* yp = (float4*)(YP + ((size_t)tn * NN + n0 + 1) * 12);
    yp[0] = make_float4(acc1[0], acc1[1], acc1[2], acc1[3]);
    yp[1] = make_float4(acc1[4], acc1[5], acc1[6], acc1[7]);
    yp[2] = make_float4(acc1[8], acc1[9], acc1[10], acc1[11]);
  }
}

// Panel-per-XCD CSR gather with node-pair ILP; edge offsets pre-multiplied
// by 12 before the shfl so the shfl yields the element offset directly.
__global__ __launch_bounds__(256, 6)
void k_agg(const float* __restrict__ YP,
           const float* __restrict__ norm_in, const float* __restrict__ cw,
           const int* __restrict__ row_ptr, const unsigned short* __restrict__ edge_src,
           const float* __restrict__ b1, float* __restrict__ svec) {
  __shared__ float red[12];
  const int tid = threadIdx.x;
  if (tid < 12) red[tid] = 0.f;
  __syncthreads();

  const int panel = blockIdx.x & 7;
  const int bp    = blockIdx.x >> 3;
  const int g = tid >> 5, l = tid & 31;
  const int ei = l / 3;
  const int q4 = (l - 3 * ei) * 4;          // element offset of this lane's quad
  const bool act = (l < 24);

  const float* Yp = YP + (size_t)panel * NN * 12;
  float4 b4 = make_float4(0.f, 0.f, 0.f, 0.f);
  if (l < 3) b4 = ((const float4*)b1)[3 * panel + l];

  float a0 = 0.f, a1 = 0.f, a2 = 0.f, a3 = 0.f;

  const int gid = bp * 8 + g;
  for (int n = gid; n < NN; n += 4096) {
    const int m = n + 2048;
    const bool hb = (m < NN);
    int e1a = row_ptr[n + 1], basea = row_ptr[n];
    int e1b = 0, baseb = 0;
    if (hb) { e1b = row_ptr[m + 1]; baseb = row_ptr[m]; }
    float va0 = 0.f, va1 = 0.f, va2 = 0.f, va3 = 0.f;
    float vb0 = 0.f, vb1 = 0.f, vb2 = 0.f, vb3 = 0.f;

    while (basea < e1a || baseb < e1b) {
      int cnta = min(32, e1a - basea);
      int cntb = min(32, e1b - baseb);
      int esa = 0, esb = 0;
      if (basea + l < e1a) esa = edge_src[basea + l] * 12;
      if (baseb + l < e1b) esb = edge_src[baseb + l] * 12;

      if (cnta > 0) {
        int s0 = __shfl(esa, ei, 32);
        float4 f0 = make_float4(0.f, 0.f, 0.f, 0.f);
        if (act && ei < cnta) f0 = *(const float4*)(Yp + s0 + q4);
        if (cnta > 8) {
          int s1 = __shfl(esa, 8 + ei, 32);
          float4 f1 = make_float4(0.f, 0.f, 0.f, 0.f);
          if (act && 8 + ei < cnta) f1 = *(const float4*)(Yp + s1 + q4);
          f0.x += f1.x; f0.y += f1.y; f0.z += f1.z; f0.w += f1.w;
        }
        if (cnta > 16) {
          int s2 = __shfl(esa, 16 + ei, 32);
          int s3 = __shfl(esa, 24 + ei, 32);
          float4 f2 = make_float4(0.f, 0.f, 0.f, 0.f), f3 = f2;
          if (act && 16 + ei < cnta) f2 = *(const float4*)(Yp + s2 + q4);
          if (act && 24 + ei < cnta) f3 = *(const float4*)(Yp + s3 + q4);
          f0.x += f2.x + f3.x; f0.y += f2.y + f3.y;
          f0.z += f2.z + f3.z; f0.w += f2.w + f3.w;
        }
        va0 += f0.x; va1 += f0.y; va2 += f0.z; va3 += f0.w;
      }
      if (cntb > 0) {
        int s0 = __shfl(esb, ei, 32);
        float4 f0 = make_float4(0.f, 0.f, 0.f, 0.f);
        if (act && ei < cntb) f0 = *(const float4*)(Yp + s0 + q4);
        if (cntb > 8) {
          int s1 = __shfl(esb, 8 + ei, 32);
          float4 f1 = make_float4(0.f, 0.f, 0.f, 0.f);
          if (act && 8 + ei < cntb) f1 = *(const float4*)(Yp + s1 + q4);
          f0.x += f1.x; f0.y += f1.y; f0.z += f1.z; f0.w += f1.w;
        }
        if (cntb > 16) {
          int s2 = __shfl(esb, 16 + ei, 32);
          int s3 = __shfl(esb, 24 + ei, 32);
          float4 f2 = make_float4(0.f, 0.f, 0.f, 0.f), f3 = f2;
          if (act && 16 + ei < cntb) f2 = *(const float4*)(Yp + s2 + q4);
          if (act && 24 + ei < cntb) f3 = *(const float4*)(Yp + s3 + q4);
          f0.x += f2.x + f3.x; f0.y += f2.y + f3.y;
          f0.z += f2.z + f3.z; f0.w += f2.w + f3.w;
        }
        vb0 += f0.x; vb1 += f0.y; vb2 += f0.z; vb3 += f0.w;
      }
      basea += 32; baseb += 32;
    }

    // reduce across the 8 edge slots (lanes 3k+q -> lanes 0..2)
    va0 += __shfl(va0, l + 12, 32); va1 += __shfl(va1, l + 12, 32);
    va2 += __shfl(va2, l + 12, 32); va3 += __shfl(va3, l + 12, 32);
    va0 += __shfl(va0, l + 6, 32);  va1 += __shfl(va1, l + 6, 32);
    va2 += __shfl(va2, l + 6, 32);  va3 += __shfl(va3, l + 6, 32);
    va0 += __shfl(va0, l + 3, 32);  va1 += __shfl(va1, l + 3, 32);
    va2 += __shfl(va2, l + 3, 32);  va3 += __shfl(va3, l + 3, 32);

    vb0 += __shfl(vb0, l + 12, 32); vb1 += __shfl(vb1, l + 12, 32);
    vb2 += __shfl(vb2, l + 12, 32); vb3 += __shfl(vb3, l + 12, 32);
    vb0 += __shfl(vb0, l + 6, 32);  vb1 += __shfl(vb1, l + 6, 32);
    vb2 += __shfl(vb2, l + 6, 32);  vb3 += __shfl(vb3, l + 6, 32);
    vb0 += __shfl(vb0, l + 3, 32);  vb1 += __shfl(vb1, l + 3, 32);
    vb2 += __shfl(vb2, l + 3, 32);  vb3 += __shfl(vb3, l + 3, 32);

    if (l < 3) {
      float ni = norm_in[n], c = cw[n];
      a0 += c * fmaxf(fmaf(ni, va0, b4.x), 0.f);
      a1 += c * fmaxf(fmaf(ni, va1, b4.y), 0.f);
      a2 += c * fmaxf(fmaf(ni, va2, b4.z), 0.f);
      a3 += c * fmaxf(fmaf(ni, va3, b4.w), 0.f);
      if (hb) {
        float nib = norm_in[m], cb = cw[m];
        a0 += cb * fmaxf(fmaf(nib, vb0, b4.x), 0.f);
        a1 += cb * fmaxf(fmaf(nib, vb1, b4.y), 0.f);
        a2 += cb * fmaxf(fmaf(nib, vb2, b4.z), 0.f);
        a3 += cb * fmaxf(fmaf(nib, vb3, b4.w), 0.f);
      }
    }
  }

  if (l < 3) {
    atomicAdd(&red[4 * l + 0], a0);
    atomicAdd(&red[4 * l + 1], a1);
    atomicAdd(&red[4 * l + 2], a2);
    atomicAdd(&red[4 * l + 3], a3);
  }
  __syncthreads();
  if (tid < 12) atomicAdd(&svec[12 * panel + tid], red[tid]);
}

// hg = (svec/N) @ W2 + b2 ; out = hg @ Wr^T + br
__global__ void k_final(const float* __restrict__ svec,
                        const float* __restrict__ W2, const float* __restrict__ b2,
                        const float* __restrict__ Wr, const float* __restrict__ br,
                        float* __restrict__ out) {
  __shared__ float hg[96];
  int j = threadIdx.x;
  if (j < 96) {
    float acc = b2[j];
    const float invN = 1.0f / (float)NN;
    for (int k = 0; k < 96; ++k)
      acc = fmaf(svec[k] * invN, W2[k * 96 + j], acc);
    hg[j] = acc;
  }
  __syncthreads();
  if (j < 8) {
    float acc = br[j];
    for (int k = 0; k < 96; ++k)
      acc = fmaf(hg[k], Wr[j * 96 + k], acc);
    out[j] = acc;
  }
}

extern "C" void kernel_launch(void* const* d_in, const int* in_sizes, int n_in,
                              void* d_out, int out_size, void* d_ws, size_t ws_size,
                              hipStream_t stream) {
  const float* feats = (const float*)d_in[0];
  const int*   src   = (const int*)d_in[1];
  const int*   dst   = (const int*)d_in[2];
  const float* W1    = (const float*)d_in[3];
  const float* b1    = (const float*)d_in[4];
  const float* W2    = (const float*)d_in[5];
  const float* b2    = (const float*)d_in[6];
  const float* Wr    = (const float*)d_in[7];
  const float* br    = (const float*)d_in[8];
  float* out = (float*)d_out;

  int*   wsi      = (int*)d_ws;
  float* wsf      = (float*)d_ws;
  float* svec     = wsf + OFF_SVEC;
  int*   bcur_d   = wsi + OFF_BCURD;
  int*   bcur_s   = wsi + OFF_BCURS;
  float* norm_out = wsf + OFF_NORM_OUT;
  float* norm_in  = wsf + OFF_NORM_IN;
  float* cw       = wsf + OFF_CW;
  int*   row_ptr  = wsi + OFF_ROW_PTR;
  unsigned short* edge_src = (unsigned short*)(wsi + OFF_EDGE_SRC);
  int*   pd       = wsi + OFF_PD;
  int*   ps       = wsi + OFF_PS;
  float* YP       = wsf + OFF_YP;        // aliases pd+ps (both dead by k_xform)

  hipMemsetAsync(d_ws, 0, ZERO_BYTES, stream);   // svec + padded cursors

  k_part<<<(NE + 2047) / 2048, 256, 0, stream>>>(src, dst, bcur_d, bcur_s, pd, ps);
  k_csr<<<NB, 256, 0, stream>>>(pd, bcur_d, row_ptr, norm_in, edge_src);
  k_bin_src<<<NB, 256, 0, stream>>>(ps, bcur_s, norm_in, norm_out, cw);
  k_xform<<<(NN + 63) / 64, 256, 0, stream>>>(feats, norm_out, W1, YP);
  k_agg<<<2048, 256, 0, stream>>>(YP, norm_in, cw, row_ptr, edge_src, b1, svec);
  k_final<<<1, 128, 0, stream>>>(svec, W2, b2, Wr, br, out);
}